// Round 11
// baseline (71.421 us; speedup 1.0000x reference)
//
#include <hip/hip_runtime.h>

#define BN_EPS 1e-5f

typedef const float* fp;
typedef float f32x4 __attribute__((ext_vector_type(4)));
typedef _Float16 f16x2 __attribute__((ext_vector_type(2)));
typedef _Float16 f16x4 __attribute__((ext_vector_type(4)));
typedef _Float16 f16x8 __attribute__((ext_vector_type(8)));

// fast transcendentals: identical formulas to the previous (passing) kernel.
__device__ __forceinline__ float frcp(float x) { return __builtin_amdgcn_rcpf(x); }
__device__ __forceinline__ float sigm(float x) { return frcp(1.0f + __expf(-x)); }
__device__ __forceinline__ float tanh_fast(float x) { return 1.0f - 2.0f * frcp(1.0f + __expf(2.0f * x)); }

__device__ __forceinline__ f32x4 ld4(const float* p) { return *(const f32x4*)p; }
__device__ __forceinline__ float dot4(f32x4 a, f32x4 b) {
    return a[0] * b[0] + a[1] * b[1] + a[2] * b[2] + a[3] * b[3];
}

#define MFMA32(A, B, C) __builtin_amdgcn_mfma_f32_16x16x32_f16((A), (B), (C), 0, 0, 0)

// async global->LDS, 16B per lane; dest = uniform base + lane*16 (HW rule).
#define GLDS16(gp, lp) __builtin_amdgcn_global_load_lds( \
    (const __attribute__((address_space(1))) void*)(gp), \
    (__attribute__((address_space(3))) void*)(lp), 16, 0, 0)

// pack f32x4 -> f16x4 via v_cvt_pkrtz (2 inst).
__device__ __forceinline__ f16x4 pk_f16(f32x4 v) {
    f16x2 lo = __builtin_bit_cast(f16x2, __builtin_amdgcn_cvt_pkrtz(v[0], v[1]));
    f16x2 hi = __builtin_bit_cast(f16x2, __builtin_amdgcn_cvt_pkrtz(v[2], v[3]));
    return __builtin_shufflevector(lo, hi, 0, 1, 2, 3);
}

// ---------------------------------------------------------------------------
// K0: zero stats1[96] + stats2[32].
// ---------------------------------------------------------------------------
__global__ void k_zero(float* __restrict__ stats) { stats[threadIdx.x] = 0.f; }

// ---------------------------------------------------------------------------
// K2: MFMA GRU, TWO independent chains per wave (32 samples/wave, 1024 waves,
// 1 wave/SIMD, 1 block/CU). Lane l: s=l&15, hi=l>>4; chain c owns sample
// base + c*16 + s. The two chains' per-step instruction streams are fully
// independent -> compiler interleaves them, filling each chain's serial
// MFMA->exp->rcp chain bubbles (wave-level round-robin failed to do this).
// Gather stays glds-pipelined: 2 glds/step (one per chain, slot-major order),
// counted fence vmcnt(4); ids in LDS (stride 53, conflict-free). Numerics
// per chain identical to the previous passing kernel.
// ---------------------------------------------------------------------------
__device__ __forceinline__ void gru_step2(
    f32x4 e0, f32x4 e1,
    const f16x8& Ar, const f16x8& ArL, const f16x8& Az, const f16x8& AzL,
    const f16x8& Anx, const f16x8& Anh,
    const f32x4& br4, const f32x4& bz4, const f32x4& bxn4, const f32x4& bhn4,
    f32x4& h0, f32x4& hs0, f16x4& hh0,
    f32x4& h1, f32x4& hs1, f16x4& hh1)
{
    f16x4 eh0 = pk_f16(e0);
    f16x4 eh1 = pk_f16(e1);
    f16x8 Bhh0 = __builtin_shufflevector(eh0, hh0, 0, 1, 2, 3, 4, 5, 6, 7);
    f16x8 Bhh1 = __builtin_shufflevector(eh1, hh1, 0, 1, 2, 3, 4, 5, 6, 7);
    f16x8 Bee0 = __builtin_shufflevector(eh0, eh0, 0, 1, 2, 3, 0, 1, 2, 3);
    f16x8 Bee1 = __builtin_shufflevector(eh1, eh1, 0, 1, 2, 3, 0, 1, 2, 3);
    f16x8 Bh20 = __builtin_shufflevector(hh0, hh0, 0, 1, 2, 3, 0, 1, 2, 3);
    f16x8 Bh21 = __builtin_shufflevector(hh1, hh1, 0, 1, 2, 3, 0, 1, 2, 3);
    f32x4 aR0 = MFMA32(Ar, Bhh0, MFMA32(ArL, Bhh0, br4));
    f32x4 aR1 = MFMA32(Ar, Bhh1, MFMA32(ArL, Bhh1, br4));
    f32x4 aZ0 = MFMA32(Az, Bhh0, MFMA32(AzL, Bhh0, bz4));
    f32x4 aZ1 = MFMA32(Az, Bhh1, MFMA32(AzL, Bhh1, bz4));
    f32x4 xn0 = MFMA32(Anx, Bee0, bxn4);
    f32x4 xn1 = MFMA32(Anx, Bee1, bxn4);
    f32x4 hn0 = MFMA32(Anh, Bh20, bhn4);
    f32x4 hn1 = MFMA32(Anh, Bh21, bhn4);
    f32x4 r0, r1, z0, z1, nv0, nv1;
#pragma unroll
    for (int q = 0; q < 4; ++q) {
        r0[q] = sigm(aR0[q]); r1[q] = sigm(aR1[q]);
        z0[q] = sigm(aZ0[q]); z1[q] = sigm(aZ1[q]);
    }
    f32x4 pre0 = r0 * hn0 + xn0;
    f32x4 pre1 = r1 * hn1 + xn1;
#pragma unroll
    for (int q = 0; q < 4; ++q) {
        nv0[q] = tanh_fast(pre0[q]);
        nv1[q] = tanh_fast(pre1[q]);
    }
    h0 = z0 * (h0 - nv0) + nv0;
    h1 = z1 * (h1 - nv1) + nv1;
    hs0 += h0;
    hs1 += h1;
    hh0 = pk_f16(h0);
    hh1 = pk_f16(h1);
}

// per-chain epilogue: degenerate MHA -> avg, target emb, user emb
__device__ __forceinline__ void epi_chain(
    int ti, int tc, int uid, int hi, f32x4 hsum,
    fp item_table, fp cat_table, fp user_table,
    fp mha_Win, fp mha_bin, fp mha_Wout, fp mha_bout,
    f32x4& avg_o, f32x4& t4_o, f32x4& u4_o)
{
    const float* itr = item_table + (size_t)ti * 12;
    f32x4 tv0 = ld4(itr), tv1 = ld4(itr + 4), tv2 = ld4(itr + 8);
    f32x4 tv3 = ld4(cat_table + tc * 4);

    f32x4 vq;
#pragma unroll
    for (int q = 0; q < 4; ++q) {
        int row = 32 + 4 * hi + q;
        const float* wv = mha_Win + row * 16;
        vq[q] = mha_bin[row] + dot4(ld4(wv), tv0) + dot4(ld4(wv + 4), tv1)
              + dot4(ld4(wv + 8), tv2) + dot4(ld4(wv + 12), tv3);
    }
    f32x4 vg0, vg1, vg2, vg3;
#pragma unroll
    for (int q = 0; q < 4; ++q) {
        vg0[q] = __shfl_xor(vq[q], (hi ^ 0) << 4);
        vg1[q] = __shfl_xor(vq[q], (hi ^ 1) << 4);
        vg2[q] = __shfl_xor(vq[q], (hi ^ 2) << 4);
        vg3[q] = __shfl_xor(vq[q], (hi ^ 3) << 4);
    }
    f32x4 aj;
#pragma unroll
    for (int q = 0; q < 4; ++q) {
        int row = 4 * hi + q;
        const float* wo = mha_Wout + row * 16;
        aj[q] = mha_bout[row] + dot4(ld4(wo), vg0) + dot4(ld4(wo + 4), vg1)
              + dot4(ld4(wo + 8), vg2) + dot4(ld4(wo + 12), vg3);
    }
    avg_o = aj * hsum;
    u4_o  = ld4(user_table + (size_t)uid * 16 + 4 * hi);
    t4_o  = (hi == 0) ? tv0 : (hi == 1) ? tv1 : (hi == 2) ? tv2 : tv3;
}

__global__ __launch_bounds__(256, 1) void k_gru(
    const int* __restrict__ user_id, const int* __restrict__ hist_item,
    const int* __restrict__ hist_cat, const int* __restrict__ tgt_item,
    const int* __restrict__ tgt_cat,
    fp user_table, fp item_table, fp cat_table,
    fp Whh, fp bhh, fp Wih, fp bih,
    fp mha_Win, fp mha_bin, fp mha_Wout, fp mha_bout,
    float* __restrict__ all_enc, float* __restrict__ stats1, int B, int T)
{
    __shared__ float    s_stage[4][2][4][256];  // 32KB [wave][chain][slot][lane*4]
    __shared__ unsigned s_ids[4][32 * 53];      // 27KB, row=(c*16+s)*53, T<=53
    __shared__ float    lds_part[4][96];

    const int tid  = threadIdx.x;
    const int lane = tid & 63;
    const int wid  = tid >> 6;
    const int s    = lane & 15;
    const int hi   = lane >> 4;

    long b0 = (long)blockIdx.x * 128 + wid * 32 + s;
    long b1 = b0 + 16;
    const bool act0 = (b0 < B), act1 = (b1 < B);
    if (!act0) b0 = B - 1;
    if (!act1) b1 = B - 1;

    // epilogue indices: materialize before the barrier (VMEM retires there)
    const int ti0 = tgt_item[b0], tc0 = tgt_cat[b0], uid0 = user_id[b0];
    const int ti1 = tgt_item[b1], tc1 = tgt_cat[b1], uid1 = user_id[b1];
    asm volatile("" :: "v"(ti0), "v"(tc0), "v"(uid0), "v"(ti1), "v"(tc1), "v"(uid1));

    // one-time packed id preload into LDS
    {
        const int* ip0 = hist_item + b0 * T;
        const int* cp0 = hist_cat  + b0 * T;
        const int* ip1 = hist_item + b1 * T;
        const int* cp1 = hist_cat  + b1 * T;
        unsigned* d0 = &s_ids[wid][s * 53];
        unsigned* d1 = &s_ids[wid][(16 + s) * 53];
        for (int k = hi; k < T; k += 4) {
            d0[k] = (unsigned)ip0[k] | ((unsigned)cp0[k] << 16);
            d1[k] = (unsigned)ip1[k] | ((unsigned)cp1[k] << 16);
        }
    }

    // ---- weight fragments + constant gate biases (shared by both chains) ----
    f32x4 wirf = ld4(&Wih[(0  + s) * 16 + 4 * hi]);
    f32x4 wizf = ld4(&Wih[(16 + s) * 16 + 4 * hi]);
    f32x4 winf = ld4(&Wih[(32 + s) * 16 + 4 * hi]);
    f32x4 whrf = ld4(&Whh[(0  + s) * 16 + 4 * hi]);
    f32x4 whzf = ld4(&Whh[(16 + s) * 16 + 4 * hi]);
    f32x4 whnf = ld4(&Whh[(32 + s) * 16 + 4 * hi]);
    f16x4 wir_h = __builtin_convertvector(wirf, f16x4);
    f16x4 wiz_h = __builtin_convertvector(wizf, f16x4);
    f16x4 win_h = __builtin_convertvector(winf, f16x4);
    f16x4 whr_h = __builtin_convertvector(whrf, f16x4);
    f16x4 whz_h = __builtin_convertvector(whzf, f16x4);
    f16x4 whn_h = __builtin_convertvector(whnf, f16x4);
    f16x4 wir_l = __builtin_convertvector(wirf - __builtin_convertvector(wir_h, f32x4), f16x4);
    f16x4 wiz_l = __builtin_convertvector(wizf - __builtin_convertvector(wiz_h, f32x4), f16x4);
    f16x4 win_l = __builtin_convertvector(winf - __builtin_convertvector(win_h, f32x4), f16x4);
    f16x4 whr_l = __builtin_convertvector(whrf - __builtin_convertvector(whr_h, f32x4), f16x4);
    f16x4 whz_l = __builtin_convertvector(whzf - __builtin_convertvector(whz_h, f32x4), f16x4);
    f16x4 whn_l = __builtin_convertvector(whnf - __builtin_convertvector(whn_h, f32x4), f16x4);
    f16x8 Ar  = __builtin_shufflevector(wir_h, whr_h, 0, 1, 2, 3, 4, 5, 6, 7);
    f16x8 ArL = __builtin_shufflevector(wir_l, whr_l, 0, 1, 2, 3, 4, 5, 6, 7);
    f16x8 Az  = __builtin_shufflevector(wiz_h, whz_h, 0, 1, 2, 3, 4, 5, 6, 7);
    f16x8 AzL = __builtin_shufflevector(wiz_l, whz_l, 0, 1, 2, 3, 4, 5, 6, 7);
    f16x8 Anx = __builtin_shufflevector(win_h, win_l, 0, 1, 2, 3, 4, 5, 6, 7);
    f16x8 Anh = __builtin_shufflevector(whn_h, whn_l, 0, 1, 2, 3, 4, 5, 6, 7);
    const f32x4 br4  = ld4(&bih[4 * hi])      + ld4(&bhh[4 * hi]);
    const f32x4 bz4  = ld4(&bih[16 + 4 * hi]) + ld4(&bhh[16 + 4 * hi]);
    const f32x4 bxn4 = ld4(&bih[32 + 4 * hi]);
    const f32x4 bhn4 = ld4(&bhh[32 + 4 * hi]);

    f32x4 h0 = {0.f,0.f,0.f,0.f}, hs0 = {0.f,0.f,0.f,0.f};
    f32x4 h1 = {0.f,0.f,0.f,0.f}, hs1 = {0.f,0.f,0.f,0.f};
    f16x4 hh0 = {}, hh1 = {};

    __syncthreads();   // ids ready; all prologue VMEM drained here

    const int T1 = T - 1;
    const unsigned* ids0 = &s_ids[wid][s * 53];
    const unsigned* ids1 = &s_ids[wid][(16 + s) * 53];
    float* stg0 = &s_stage[wid][0][0][0];
    float* stg1 = &s_stage[wid][1][0][0];
    const int l4 = lane * 4;

    // per-lane gather parameters
    const char*   gb   = (hi < 3) ? (const char*)item_table + hi * 16
                                  : (const char*)cat_table;
    const unsigned gsh  = (hi < 3) ? 0u : 16u;
    const unsigned gmul = (hi < 3) ? 48u : 16u;
#define GADDR(pk) (gb + (size_t)(((pk) >> gsh) & 0xffffu) * gmul)

    // prologue: stage slots 0..3 for both chains, slot-major issue order
#pragma unroll
    for (int d = 0; d < 4; ++d) {
        int td = (d > T1) ? T1 : d;
        unsigned p0 = ids0[td], p1 = ids1[td];
        GLDS16(GADDR(p0), stg0 + d * 256);
        GLDS16(GADDR(p1), stg1 + d * 256);
    }
    unsigned idA0 = ids0[(4 > T1) ? T1 : 4];
    unsigned idA1 = ids1[(4 > T1) ? T1 : 4];
    asm volatile("s_waitcnt vmcnt(6)" ::: "memory");
    f32x4 eCur0 = ld4(stg0 + l4);
    f32x4 eCur1 = ld4(stg1 + l4);

    for (int t = 0; t < T; ++t) {
        // oldest 4 retired => slot t+1 landed for both chains; DS WAR clear
        asm volatile("s_waitcnt vmcnt(4) lgkmcnt(0)" ::: "memory");
        GLDS16(GADDR(idA0), stg0 + ((t & 3) << 8));            // stage t+4 c0
        GLDS16(GADDR(idA1), stg1 + ((t & 3) << 8));            // stage t+4 c1
        f32x4 eN0 = ld4(stg0 + (((t + 1) & 3) << 8) + l4);
        f32x4 eN1 = ld4(stg1 + (((t + 1) & 3) << 8) + l4);
        int t5 = (t + 5 > T1) ? T1 : t + 5;
        unsigned idB0 = ids0[t5], idB1 = ids1[t5];

        gru_step2(eCur0, eCur1, Ar, ArL, Az, AzL, Anx, Anh,
                  br4, bz4, bxn4, bhn4, h0, hs0, hh0, h1, hs1, hh1);

        idA0 = idB0; idA1 = idB1;
        eCur0 = eN0; eCur1 = eN1;
    }

    // ---- epilogue: both chains ----
    f32x4 avg0, t40, u40, avg1, t41, u41;
    epi_chain(ti0, tc0, uid0, hi, hs0, item_table, cat_table, user_table,
              mha_Win, mha_bin, mha_Wout, mha_bout, avg0, t40, u40);
    epi_chain(ti1, tc1, uid1, hi, hs1, item_table, cat_table, user_table,
              mha_Win, mha_bin, mha_Wout, mha_bout, avg1, t41, u41);

    if (act0) {
        float* er = all_enc + b0 * 48 + 4 * hi;
        *(f32x4*)er        = avg0;
        *(f32x4*)(er + 16) = t40;
        *(f32x4*)(er + 32) = u40;
    }
    if (act1) {
        float* er = all_enc + b1 * 48 + 4 * hi;
        *(f32x4*)er        = avg1;
        *(f32x4*)(er + 16) = t41;
        *(f32x4*)(er + 32) = u41;
    }

    const f32x4 zero4 = {0.f, 0.f, 0.f, 0.f};
    f32x4 a0 = act0 ? avg0 : zero4, t0v = act0 ? t40 : zero4, u0v = act0 ? u40 : zero4;
    f32x4 a1 = act1 ? avg1 : zero4, t1v = act1 ? t41 : zero4, u1v = act1 ? u41 : zero4;
    f32x4 sa = a0 + a1, st = t0v + t1v, su = u0v + u1v;
    f32x4 qa = a0 * a0 + a1 * a1, qt = t0v * t0v + t1v * t1v, qu = u0v * u0v + u1v * u1v;
#pragma unroll
    for (int m = 1; m <= 8; m <<= 1) {
#pragma unroll
        for (int q = 0; q < 4; ++q) {
            sa[q] += __shfl_xor(sa[q], m);
            st[q] += __shfl_xor(st[q], m);
            su[q] += __shfl_xor(su[q], m);
            qa[q] += __shfl_xor(qa[q], m);
            qt[q] += __shfl_xor(qt[q], m);
            qu[q] += __shfl_xor(qu[q], m);
        }
    }
    if (s == 0) {
        int c = 4 * hi;
#pragma unroll
        for (int q = 0; q < 4; ++q) {
            lds_part[wid][c + q]      = sa[q];
            lds_part[wid][16 + c + q] = st[q];
            lds_part[wid][32 + c + q] = su[q];
            lds_part[wid][48 + c + q] = qa[q];
            lds_part[wid][64 + c + q] = qt[q];
            lds_part[wid][80 + c + q] = qu[q];
        }
    }
    __syncthreads();
    if (tid < 96) {
        float v = lds_part[0][tid] + lds_part[1][tid] + lds_part[2][tid] + lds_part[3][tid];
        atomicAdd(&stats1[tid], v);
    }
}

// ---------------------------------------------------------------------------
// K3: fc1 with BN1-fold computed inline per block.
// ---------------------------------------------------------------------------
__global__ __launch_bounds__(256) void k_fc1(
    const float* __restrict__ all_enc, const float* __restrict__ stats,
    fp fc1_W, fp fc1_b, fp g1, fp b1,
    float* __restrict__ hbuf, float* __restrict__ stats2, int B)
{
    const int tid = threadIdx.x, lane = tid & 63, wid = tid >> 6;
    const int j = lane & 15, sl = lane >> 4;
    __shared__ float kk[48], mm[48];
    __shared__ float part[4][32];

    if (tid < 48) {
        float mu  = stats[tid] / (float)B;
        float var = stats[48 + tid] / (float)B - mu * mu;
        float k   = rsqrtf(var + BN_EPS);
        float gk  = g1[tid] * k;
        kk[tid] = gk;
        mm[tid] = b1[tid] - mu * gk;
    }
    __syncthreads();

    float w[48];
    float bj = fc1_b[j];
#pragma unroll
    for (int q = 0; q < 12; ++q) {
        float4 v = *(const float4*)&fc1_W[j * 48 + q * 4];
        w[q * 4 + 0] = v.x * kk[q * 4 + 0];
        w[q * 4 + 1] = v.y * kk[q * 4 + 1];
        w[q * 4 + 2] = v.z * kk[q * 4 + 2];
        w[q * 4 + 3] = v.w * kk[q * 4 + 3];
        bj += v.x * mm[q * 4 + 0] + v.y * mm[q * 4 + 1]
            + v.z * mm[q * 4 + 2] + v.w * mm[q * 4 + 3];
    }

    float sh = 0.f, sq = 0.f;
    for (long b = (long)blockIdx.x * 16 + wid * 4 + sl; b < B; b += (long)gridDim.x * 16) {
        const float* x = all_enc + b * 48;
        float acc = bj;
#pragma unroll
        for (int q = 0; q < 12; ++q) {
            float4 v = *(const float4*)&x[q * 4];
            acc += w[q * 4] * v.x + w[q * 4 + 1] * v.y + w[q * 4 + 2] * v.z + w[q * 4 + 3] * v.w;
        }
        float h = fmaxf(acc, 0.f);
        hbuf[b * 16 + j] = h;
        sh += h; sq += h * h;
    }
    sh += __shfl_xor(sh, 16); sh += __shfl_xor(sh, 32);
    sq += __shfl_xor(sq, 16); sq += __shfl_xor(sq, 32);
    if (sl == 0) { part[wid][j] = sh; part[wid][16 + j] = sq; }
    __syncthreads();
    if (tid < 32) {
        float v = part[0][tid] + part[1][tid] + part[2][tid] + part[3][tid];
        atomicAdd(&stats2[tid], v);
    }
}

// ---------------------------------------------------------------------------
// K4: logits + softmax, BN2-fold computed inline per block.
// ---------------------------------------------------------------------------
__global__ __launch_bounds__(256) void k_out(
    const float* __restrict__ hbuf, const float* __restrict__ stats2,
    fp fc2_W, fp fc2_b, fp g2, fp b2, float* __restrict__ out, int B)
{
    __shared__ float w[34];
    const int tid = threadIdx.x;
    if (tid < 32) {
        int c = tid & 15;
        float mu  = stats2[c] / (float)B;
        float var = stats2[16 + c] / (float)B - mu * mu;
        float gk  = g2[c] * rsqrtf(var + BN_EPS);
        w[tid] = fc2_W[tid] * gk;
    }
    if (tid < 2) {
        float acc = fc2_b[tid];
        for (int c = 0; c < 16; ++c) {
            float mu  = stats2[c] / (float)B;
            float var = stats2[16 + c] / (float)B - mu * mu;
            float gk  = g2[c] * rsqrtf(var + BN_EPS);
            acc += fc2_W[tid * 16 + c] * (b2[c] - mu * gk);
        }
        w[32 + tid] = acc;
    }
    __syncthreads();
    for (long b = (long)blockIdx.x * blockDim.x + threadIdx.x; b < B;
         b += (long)gridDim.x * blockDim.x) {
        const float* h = hbuf + b * 16;
        float l0 = w[32], l1 = w[33];
#pragma unroll
        for (int q = 0; q < 4; ++q) {
            float4 v = *(const float4*)&h[q * 4];
            l0 += w[q * 4] * v.x + w[q * 4 + 1] * v.y + w[q * 4 + 2] * v.z + w[q * 4 + 3] * v.w;
            l1 += w[16 + q * 4] * v.x + w[17 + q * 4] * v.y + w[18 + q * 4] * v.z + w[19 + q * 4] * v.w;
        }
        float m  = fmaxf(l0, l1);
        float e0 = __expf(l0 - m), e1 = __expf(l1 - m);
        float inv = frcp(e0 + e1);
        float2 p; p.x = e0 * inv; p.y = e1 * inv;
        *(float2*)&out[b * 2] = p;
    }
}

// ---------------------------------------------------------------------------
extern "C" void kernel_launch(void* const* d_in, const int* in_sizes, int n_in,
                              void* d_out, int out_size, void* d_ws, size_t ws_size,
                              hipStream_t stream)
{
    const int* user_id   = (const int*)d_in[0];
    const int* hist_item = (const int*)d_in[1];
    const int* hist_cat  = (const int*)d_in[2];
    const int* tgt_item  = (const int*)d_in[3];
    const int* tgt_cat   = (const int*)d_in[4];
    fp user_table = (fp)d_in[5];
    fp item_table = (fp)d_in[6];
    fp cat_table  = (fp)d_in[7];
    fp Wih = (fp)d_in[8],  Whh = (fp)d_in[9];
    fp bih = (fp)d_in[10], bhh = (fp)d_in[11];
    fp Win = (fp)d_in[12], binp = (fp)d_in[13];
    fp Wout = (fp)d_in[14], bout = (fp)d_in[15];
    fp g1 = (fp)d_in[16], b1 = (fp)d_in[17];
    fp fc1W = (fp)d_in[18], fc1b = (fp)d_in[19];
    fp g2 = (fp)d_in[20], b2 = (fp)d_in[21];
    fp fc2W = (fp)d_in[22], fc2b = (fp)d_in[23];

    const int B = in_sizes[0];
    const int T = in_sizes[1] / B;

    float* ws       = (float*)d_ws;
    float* stats1   = ws;                       // 96
    float* stats2   = ws + 96;                  // 32
    float* all_enc  = ws + 128;                 // B*48 (16B aligned)
    float* hbuf     = all_enc + (size_t)B * 48; // B*16

    hipLaunchKernelGGL(k_zero, dim3(1), dim3(128), 0, stream, ws);

    hipLaunchKernelGGL(k_gru, dim3((B + 127) / 128), dim3(256), 0, stream,
                       user_id, hist_item, hist_cat, tgt_item, tgt_cat,
                       user_table, item_table, cat_table, Whh, bhh, Wih, bih,
                       Win, binp, Wout, bout, all_enc, stats1, B, T);

    hipLaunchKernelGGL(k_fc1, dim3(512), dim3(256), 0, stream,
                       all_enc, stats1, fc1W, fc1b, g1, b1, hbuf, stats2, B);

    hipLaunchKernelGGL(k_out, dim3((B + 255) / 256), dim3(256), 0, stream,
                       hbuf, stats2, fc2W, fc2b, g2, b2, (float*)d_out, B);
}

// Round 12
// 70.841 us; speedup vs baseline: 1.0082x; 1.0082x over previous
//
#include <hip/hip_runtime.h>

#define BN_EPS 1e-5f

typedef const float* fp;
typedef float f32x4 __attribute__((ext_vector_type(4)));
typedef _Float16 f16x2 __attribute__((ext_vector_type(2)));
typedef _Float16 f16x4 __attribute__((ext_vector_type(4)));
typedef _Float16 f16x8 __attribute__((ext_vector_type(8)));
typedef unsigned u32x4 __attribute__((ext_vector_type(4)));

// fast transcendentals: identical formulas to the previous (passing) kernel.
__device__ __forceinline__ float frcp(float x) { return __builtin_amdgcn_rcpf(x); }
__device__ __forceinline__ float sigm(float x) { return frcp(1.0f + __expf(-x)); }
__device__ __forceinline__ float tanh_fast(float x) { return 1.0f - 2.0f * frcp(1.0f + __expf(2.0f * x)); }

__device__ __forceinline__ f32x4 ld4(const float* p) { return *(const f32x4*)p; }
__device__ __forceinline__ float dot4(f32x4 a, f32x4 b) {
    return a[0] * b[0] + a[1] * b[1] + a[2] * b[2] + a[3] * b[3];
}

#define MFMA32(A, B, C) __builtin_amdgcn_mfma_f32_16x16x32_f16((A), (B), (C), 0, 0, 0)

// async global->LDS, 16B per lane; dest = uniform base + lane*16 (HW rule).
#define GLDS16(gp, lp) __builtin_amdgcn_global_load_lds( \
    (const __attribute__((address_space(1))) void*)(gp), \
    (__attribute__((address_space(3))) void*)(lp), 16, 0, 0)

// pack f32x4 -> f16x4 via v_cvt_pkrtz (2 inst).
__device__ __forceinline__ f16x4 pk_f16(f32x4 v) {
    f16x2 lo = __builtin_bit_cast(f16x2, __builtin_amdgcn_cvt_pkrtz(v[0], v[1]));
    f16x2 hi = __builtin_bit_cast(f16x2, __builtin_amdgcn_cvt_pkrtz(v[2], v[3]));
    return __builtin_shufflevector(lo, hi, 0, 1, 2, 3);
}

// ---------------------------------------------------------------------------
// K2: MFMA GRU, 16 samples/wave (R10 config: 2048 waves, 2/SIMD — HW wave
// interleave beats in-wave ILP, proven by R4/R11 regressions). 4-step
// unrolled loop over an 8-slot ring: ONE vmcnt(4) + ONE lgkmcnt(0) fence per
// 4 steps (was 4), ids via one ds_read_b128 per 4 steps, loop control /4,
// prefetch distance 7 steps. Iteration k consumes slots (4k..4k+3)&7 then
// restages the SAME slots for steps 4k+8..4k+11 => WAR always against
// just-consumed slots. Tail (T&3) drains with one vmcnt(0). Per-step math
// bit-identical to R10 (absmax must stay 0.00390625). Requires T <= 52.
// ---------------------------------------------------------------------------
__device__ __forceinline__ void gru_step_mf(
    f32x4 e4,
    const f16x8& Ar, const f16x8& ArL, const f16x8& Az, const f16x8& AzL,
    const f16x8& Anx, const f16x8& Anh,
    const f32x4& br4, const f32x4& bz4, const f32x4& bxn4, const f32x4& bhn4,
    f32x4& h, f32x4& hsum, f16x4& hh)
{
    f16x4 e_h = pk_f16(e4);
    f16x8 Bhh = __builtin_shufflevector(e_h, hh, 0, 1, 2, 3, 4, 5, 6, 7);
    f16x8 Bee = __builtin_shufflevector(e_h, e_h, 0, 1, 2, 3, 0, 1, 2, 3);
    f16x8 Bh2 = __builtin_shufflevector(hh, hh, 0, 1, 2, 3, 0, 1, 2, 3);
    f32x4 aR = MFMA32(Ar, Bhh, MFMA32(ArL, Bhh, br4));
    f32x4 aZ = MFMA32(Az, Bhh, MFMA32(AzL, Bhh, bz4));
    f32x4 xn = MFMA32(Anx, Bee, bxn4);
    f32x4 hn = MFMA32(Anh, Bh2, bhn4);
    f32x4 r, z, nv;
#pragma unroll
    for (int q = 0; q < 4; ++q) { r[q] = sigm(aR[q]); z[q] = sigm(aZ[q]); }
    f32x4 pre = r * hn + xn;
#pragma unroll
    for (int q = 0; q < 4; ++q) nv[q] = tanh_fast(pre[q]);
    h = z * (h - nv) + nv;
    hsum += h;
    hh = pk_f16(h);
}

__global__ __launch_bounds__(256, 2) void k_gru(
    const int* __restrict__ user_id, const int* __restrict__ hist_item,
    const int* __restrict__ hist_cat, const int* __restrict__ tgt_item,
    const int* __restrict__ tgt_cat,
    fp user_table, fp item_table, fp cat_table,
    fp Whh, fp bhh, fp Wih, fp bih,
    fp mha_Win, fp mha_bin, fp mha_Wout, fp mha_bout,
    float* __restrict__ all_enc, float* __restrict__ stats1, int B, int T)
{
    __shared__ float    s_stage[4][8][256];   // 32KB [wave][slot][lane*4]
    __shared__ unsigned s_ids[4][16 * 68];    // 17.4KB packed (cd<<16)|id, stride 68
    __shared__ float    lds_part[4][96];

    const int tid  = threadIdx.x;
    const int lane = tid & 63;
    const int wid  = tid >> 6;
    const int s    = lane & 15;
    const int hi   = lane >> 4;

    long b = (long)blockIdx.x * 64 + wid * 16 + s;
    const bool act = (b < B);
    if (!act) b = B - 1;

    // epilogue indices: materialize before the barrier (VMEM retires there)
    const int ti  = tgt_item[b];
    const int tc  = tgt_cat[b];
    const int uid = user_id[b];
    asm volatile("" :: "v"(ti), "v"(tc), "v"(uid));

    const int T1 = T - 1;

    // one-time packed id preload into LDS, padded with clamped ids to idx 63
    {
        const int* ip = hist_item + b * T;
        const int* cp = hist_cat  + b * T;
        unsigned* d = &s_ids[wid][s * 68];
        for (int k = hi; k < 64; k += 4) {
            int src = (k <= T1) ? k : T1;
            d[k] = (unsigned)ip[src] | ((unsigned)cp[src] << 16);
        }
    }

    // ---- weight fragments + constant gate biases (one-time) ----
    f32x4 wirf = ld4(&Wih[(0  + s) * 16 + 4 * hi]);
    f32x4 wizf = ld4(&Wih[(16 + s) * 16 + 4 * hi]);
    f32x4 winf = ld4(&Wih[(32 + s) * 16 + 4 * hi]);
    f32x4 whrf = ld4(&Whh[(0  + s) * 16 + 4 * hi]);
    f32x4 whzf = ld4(&Whh[(16 + s) * 16 + 4 * hi]);
    f32x4 whnf = ld4(&Whh[(32 + s) * 16 + 4 * hi]);
    f16x4 wir_h = __builtin_convertvector(wirf, f16x4);
    f16x4 wiz_h = __builtin_convertvector(wizf, f16x4);
    f16x4 win_h = __builtin_convertvector(winf, f16x4);
    f16x4 whr_h = __builtin_convertvector(whrf, f16x4);
    f16x4 whz_h = __builtin_convertvector(whzf, f16x4);
    f16x4 whn_h = __builtin_convertvector(whnf, f16x4);
    f16x4 wir_l = __builtin_convertvector(wirf - __builtin_convertvector(wir_h, f32x4), f16x4);
    f16x4 wiz_l = __builtin_convertvector(wizf - __builtin_convertvector(wiz_h, f32x4), f16x4);
    f16x4 win_l = __builtin_convertvector(winf - __builtin_convertvector(win_h, f32x4), f16x4);
    f16x4 whr_l = __builtin_convertvector(whrf - __builtin_convertvector(whr_h, f32x4), f16x4);
    f16x4 whz_l = __builtin_convertvector(whzf - __builtin_convertvector(whz_h, f32x4), f16x4);
    f16x4 whn_l = __builtin_convertvector(whnf - __builtin_convertvector(whn_h, f32x4), f16x4);
    f16x8 Ar  = __builtin_shufflevector(wir_h, whr_h, 0, 1, 2, 3, 4, 5, 6, 7);
    f16x8 ArL = __builtin_shufflevector(wir_l, whr_l, 0, 1, 2, 3, 4, 5, 6, 7);
    f16x8 Az  = __builtin_shufflevector(wiz_h, whz_h, 0, 1, 2, 3, 4, 5, 6, 7);
    f16x8 AzL = __builtin_shufflevector(wiz_l, whz_l, 0, 1, 2, 3, 4, 5, 6, 7);
    f16x8 Anx = __builtin_shufflevector(win_h, win_l, 0, 1, 2, 3, 4, 5, 6, 7);
    f16x8 Anh = __builtin_shufflevector(whn_h, whn_l, 0, 1, 2, 3, 4, 5, 6, 7);
    const f32x4 br4  = ld4(&bih[4 * hi])      + ld4(&bhh[4 * hi]);
    const f32x4 bz4  = ld4(&bih[16 + 4 * hi]) + ld4(&bhh[16 + 4 * hi]);
    const f32x4 bxn4 = ld4(&bih[32 + 4 * hi]);
    const f32x4 bhn4 = ld4(&bhh[32 + 4 * hi]);

    f32x4 h = {0.f, 0.f, 0.f, 0.f}, hsum = {0.f, 0.f, 0.f, 0.f};
    f16x4 hh = {};

    __syncthreads();   // ids ready; all prologue VMEM drained here

    const unsigned* idsrow = &s_ids[wid][s * 68];
    float* stg = &s_stage[wid][0][0];
    const int l4 = lane * 4;

    // per-lane gather parameters
    const char*   gb   = (hi < 3) ? (const char*)item_table + hi * 16
                                  : (const char*)cat_table;
    const unsigned gsh  = (hi < 3) ? 0u : 16u;
    const unsigned gmul = (hi < 3) ? 48u : 16u;
#define GADDR(pk) (gb + (size_t)(((pk) >> gsh) & 0xffffu) * gmul)

    // prologue: stage slots 0..7 (steps 0..7, clamped); prefetch ids[8..11]
    {
        u32x4 i03 = *(const u32x4*)&idsrow[0];
        u32x4 i47 = *(const u32x4*)&idsrow[4];
        GLDS16(GADDR(i03[0]), stg);
        GLDS16(GADDR(i03[1]), stg + 256);
        GLDS16(GADDR(i03[2]), stg + 512);
        GLDS16(GADDR(i03[3]), stg + 768);
        GLDS16(GADDR(i47[0]), stg + 1024);
        GLDS16(GADDR(i47[1]), stg + 1280);
        GLDS16(GADDR(i47[2]), stg + 1536);
        GLDS16(GADDR(i47[3]), stg + 1792);
    }
    u32x4 idn = *(const u32x4*)&idsrow[8];

    const int M    = T >> 2;   // full 4-step iterations
    const int tail = T & 3;

    for (int k = 0; k < M; ++k) {
        const int base = k << 2;
        // oldest 4 of 8 outstanding retired => slots for steps base..base+3 landed
        asm volatile("s_waitcnt vmcnt(4)" ::: "memory");
        f32x4 e0 = ld4(stg + (((base + 0) & 7) << 8) + l4);
        f32x4 e1 = ld4(stg + (((base + 1) & 7) << 8) + l4);
        f32x4 e2 = ld4(stg + (((base + 2) & 7) << 8) + l4);
        f32x4 e3 = ld4(stg + (((base + 3) & 7) << 8) + l4);
        u32x4 idc = idn;
        idn = *(const u32x4*)&idsrow[base + 12];   // for next iteration

        gru_step_mf(e0, Ar, ArL, Az, AzL, Anx, Anh, br4, bz4, bxn4, bhn4, h, hsum, hh);
        gru_step_mf(e1, Ar, ArL, Az, AzL, Anx, Anh, br4, bz4, bxn4, bhn4, h, hsum, hh);
        gru_step_mf(e2, Ar, ArL, Az, AzL, Anx, Anh, br4, bz4, bxn4, bhn4, h, hsum, hh);
        gru_step_mf(e3, Ar, ArL, Az, AzL, Anx, Anh, br4, bz4, bxn4, bhn4, h, hsum, hh);

        // DS reads above long retired (free) — clears WAR for re-staging
        asm volatile("s_waitcnt lgkmcnt(0)" ::: "memory");
        GLDS16(GADDR(idc[0]), stg + (((base + 0) & 7) << 8));   // step base+8
        GLDS16(GADDR(idc[1]), stg + (((base + 1) & 7) << 8));   // step base+9
        GLDS16(GADDR(idc[2]), stg + (((base + 2) & 7) << 8));   // step base+10
        GLDS16(GADDR(idc[3]), stg + (((base + 3) & 7) << 8));   // step base+11
    }
    if (tail) {
        asm volatile("s_waitcnt vmcnt(0)" ::: "memory");
        for (int t = M << 2; t < T; ++t) {
            f32x4 e = ld4(stg + ((t & 7) << 8) + l4);
            gru_step_mf(e, Ar, ArL, Az, AzL, Anx, Anh, br4, bz4, bxn4, bhn4, h, hsum, hh);
        }
    }

    // ---- epilogue: degenerate MHA -> A[b], all_enc row, BN1 stats ----
    const float* itr = item_table + (size_t)ti * 12;
    f32x4 tv0 = ld4(itr), tv1 = ld4(itr + 4), tv2 = ld4(itr + 8);
    f32x4 tv3 = ld4(cat_table + tc * 4);

    f32x4 vq;
#pragma unroll
    for (int q = 0; q < 4; ++q) {
        int row = 32 + 4 * hi + q;
        const float* wv = mha_Win + row * 16;
        vq[q] = mha_bin[row] + dot4(ld4(wv), tv0) + dot4(ld4(wv + 4), tv1)
              + dot4(ld4(wv + 8), tv2) + dot4(ld4(wv + 12), tv3);
    }
    f32x4 vg0, vg1, vg2, vg3;
#pragma unroll
    for (int q = 0; q < 4; ++q) {
        vg0[q] = __shfl_xor(vq[q], (hi ^ 0) << 4);
        vg1[q] = __shfl_xor(vq[q], (hi ^ 1) << 4);
        vg2[q] = __shfl_xor(vq[q], (hi ^ 2) << 4);
        vg3[q] = __shfl_xor(vq[q], (hi ^ 3) << 4);
    }
    f32x4 aj;
#pragma unroll
    for (int q = 0; q < 4; ++q) {
        int row = 4 * hi + q;
        const float* wo = mha_Wout + row * 16;
        aj[q] = mha_bout[row] + dot4(ld4(wo), vg0) + dot4(ld4(wo + 4), vg1)
              + dot4(ld4(wo + 8), vg2) + dot4(ld4(wo + 12), vg3);
    }
    f32x4 avg = aj * hsum;

    f32x4 u4  = ld4(user_table + (size_t)uid * 16 + 4 * hi);
    f32x4 t4v = (hi == 0) ? tv0 : (hi == 1) ? tv1 : (hi == 2) ? tv2 : tv3;

    if (act) {
        float* er = all_enc + b * 48 + 4 * hi;
        *(f32x4*)er        = avg;
        *(f32x4*)(er + 16) = t4v;
        *(f32x4*)(er + 32) = u4;
    }

    const f32x4 zero4 = {0.f, 0.f, 0.f, 0.f};
    f32x4 sa = act ? avg : zero4, st = act ? t4v : zero4, su = act ? u4 : zero4;
    f32x4 qa = sa * sa, qt = st * st, qu = su * su;
#pragma unroll
    for (int m = 1; m <= 8; m <<= 1) {
#pragma unroll
        for (int q = 0; q < 4; ++q) {
            sa[q] += __shfl_xor(sa[q], m);
            st[q] += __shfl_xor(st[q], m);
            su[q] += __shfl_xor(su[q], m);
            qa[q] += __shfl_xor(qa[q], m);
            qt[q] += __shfl_xor(qt[q], m);
            qu[q] += __shfl_xor(qu[q], m);
        }
    }
    if (s == 0) {
        int c = 4 * hi;
#pragma unroll
        for (int q = 0; q < 4; ++q) {
            lds_part[wid][c + q]      = sa[q];
            lds_part[wid][16 + c + q] = st[q];
            lds_part[wid][32 + c + q] = su[q];
            lds_part[wid][48 + c + q] = qa[q];
            lds_part[wid][64 + c + q] = qt[q];
            lds_part[wid][80 + c + q] = qu[q];
        }
    }
    __syncthreads();
    if (tid < 96) {
        float v = lds_part[0][tid] + lds_part[1][tid] + lds_part[2][tid] + lds_part[3][tid];
        atomicAdd(&stats1[tid], v);
    }
}

// ---------------------------------------------------------------------------
// K3: fc1 with BN1-fold computed inline per block.
// ---------------------------------------------------------------------------
__global__ __launch_bounds__(256) void k_fc1(
    const float* __restrict__ all_enc, const float* __restrict__ stats,
    fp fc1_W, fp fc1_b, fp g1, fp b1,
    float* __restrict__ hbuf, float* __restrict__ stats2, int B)
{
    const int tid = threadIdx.x, lane = tid & 63, wid = tid >> 6;
    const int j = lane & 15, sl = lane >> 4;
    __shared__ float kk[48], mm[48];
    __shared__ float part[4][32];

    if (tid < 48) {
        float mu  = stats[tid] / (float)B;
        float var = stats[48 + tid] / (float)B - mu * mu;
        float k   = rsqrtf(var + BN_EPS);
        float gk  = g1[tid] * k;
        kk[tid] = gk;
        mm[tid] = b1[tid] - mu * gk;
    }
    __syncthreads();

    float w[48];
    float bj = fc1_b[j];
#pragma unroll
    for (int q = 0; q < 12; ++q) {
        float4 v = *(const float4*)&fc1_W[j * 48 + q * 4];
        w[q * 4 + 0] = v.x * kk[q * 4 + 0];
        w[q * 4 + 1] = v.y * kk[q * 4 + 1];
        w[q * 4 + 2] = v.z * kk[q * 4 + 2];
        w[q * 4 + 3] = v.w * kk[q * 4 + 3];
        bj += v.x * mm[q * 4 + 0] + v.y * mm[q * 4 + 1]
            + v.z * mm[q * 4 + 2] + v.w * mm[q * 4 + 3];
    }

    float sh = 0.f, sq = 0.f;
    for (long b = (long)blockIdx.x * 16 + wid * 4 + sl; b < B; b += (long)gridDim.x * 16) {
        const float* x = all_enc + b * 48;
        float acc = bj;
#pragma unroll
        for (int q = 0; q < 12; ++q) {
            float4 v = *(const float4*)&x[q * 4];
            acc += w[q * 4] * v.x + w[q * 4 + 1] * v.y + w[q * 4 + 2] * v.z + w[q * 4 + 3] * v.w;
        }
        float h = fmaxf(acc, 0.f);
        hbuf[b * 16 + j] = h;
        sh += h; sq += h * h;
    }
    sh += __shfl_xor(sh, 16); sh += __shfl_xor(sh, 32);
    sq += __shfl_xor(sq, 16); sq += __shfl_xor(sq, 32);
    if (sl == 0) { part[wid][j] = sh; part[wid][16 + j] = sq; }
    __syncthreads();
    if (tid < 32) {
        float v = part[0][tid] + part[1][tid] + part[2][tid] + part[3][tid];
        atomicAdd(&stats2[tid], v);
    }
}

// ---------------------------------------------------------------------------
// K4: logits + softmax, BN2-fold computed inline per block.
// ---------------------------------------------------------------------------
__global__ __launch_bounds__(256) void k_out(
    const float* __restrict__ hbuf, const float* __restrict__ stats2,
    fp fc2_W, fp fc2_b, fp g2, fp b2, float* __restrict__ out, int B)
{
    __shared__ float w[34];
    const int tid = threadIdx.x;
    if (tid < 32) {
        int c = tid & 15;
        float mu  = stats2[c] / (float)B;
        float var = stats2[16 + c] / (float)B - mu * mu;
        float gk  = g2[c] * rsqrtf(var + BN_EPS);
        w[tid] = fc2_W[tid] * gk;
    }
    if (tid < 2) {
        float acc = fc2_b[tid];
        for (int c = 0; c < 16; ++c) {
            float mu  = stats2[c] / (float)B;
            float var = stats2[16 + c] / (float)B - mu * mu;
            float gk  = g2[c] * rsqrtf(var + BN_EPS);
            acc += fc2_W[tid * 16 + c] * (b2[c] - mu * gk);
        }
        w[32 + tid] = acc;
    }
    __syncthreads();
    for (long b = (long)blockIdx.x * blockDim.x + threadIdx.x; b < B;
         b += (long)gridDim.x * blockDim.x) {
        const float* h = hbuf + b * 16;
        float l0 = w[32], l1 = w[33];
#pragma unroll
        for (int q = 0; q < 4; ++q) {
            float4 v = *(const float4*)&h[q * 4];
            l0 += w[q * 4] * v.x + w[q * 4 + 1] * v.y + w[q * 4 + 2] * v.z + w[q * 4 + 3] * v.w;
            l1 += w[16 + q * 4] * v.x + w[17 + q * 4] * v.y + w[18 + q * 4] * v.z + w[19 + q * 4] * v.w;
        }
        float m  = fmaxf(l0, l1);
        float e0 = __expf(l0 - m), e1 = __expf(l1 - m);
        float inv = frcp(e0 + e1);
        float2 p; p.x = e0 * inv; p.y = e1 * inv;
        *(float2*)&out[b * 2] = p;
    }
}

// ---------------------------------------------------------------------------
extern "C" void kernel_launch(void* const* d_in, const int* in_sizes, int n_in,
                              void* d_out, int out_size, void* d_ws, size_t ws_size,
                              hipStream_t stream)
{
    const int* user_id   = (const int*)d_in[0];
    const int* hist_item = (const int*)d_in[1];
    const int* hist_cat  = (const int*)d_in[2];
    const int* tgt_item  = (const int*)d_in[3];
    const int* tgt_cat   = (const int*)d_in[4];
    fp user_table = (fp)d_in[5];
    fp item_table = (fp)d_in[6];
    fp cat_table  = (fp)d_in[7];
    fp Wih = (fp)d_in[8],  Whh = (fp)d_in[9];
    fp bih = (fp)d_in[10], bhh = (fp)d_in[11];
    fp Win = (fp)d_in[12], binp = (fp)d_in[13];
    fp Wout = (fp)d_in[14], bout = (fp)d_in[15];
    fp g1 = (fp)d_in[16], b1 = (fp)d_in[17];
    fp fc1W = (fp)d_in[18], fc1b = (fp)d_in[19];
    fp g2 = (fp)d_in[20], b2 = (fp)d_in[21];
    fp fc2W = (fp)d_in[22], fc2b = (fp)d_in[23];

    const int B = in_sizes[0];
    const int T = in_sizes[1] / B;

    float* ws       = (float*)d_ws;
    float* stats1   = ws;                       // 96
    float* stats2   = ws + 96;                  // 32
    float* all_enc  = ws + 128;                 // B*48 (16B aligned)
    float* hbuf     = all_enc + (size_t)B * 48; // B*16

    hipMemsetAsync(ws, 0, 128 * sizeof(float), stream);   // stats1 + stats2

    hipLaunchKernelGGL(k_gru, dim3((B + 63) / 64), dim3(256), 0, stream,
                       user_id, hist_item, hist_cat, tgt_item, tgt_cat,
                       user_table, item_table, cat_table, Whh, bhh, Wih, bih,
                       Win, binp, Wout, bout, all_enc, stats1, B, T);

    hipLaunchKernelGGL(k_fc1, dim3(1024), dim3(256), 0, stream,
                       all_enc, stats1, fc1W, fc1b, g1, b1, hbuf, stats2, B);

    hipLaunchKernelGGL(k_out, dim3((B + 255) / 256), dim3(256), 0, stream,
                       hbuf, stats2, fc2W, fc2b, g2, b2, (float*)d_out, B);
}

// Round 13
// 63.915 us; speedup vs baseline: 1.1174x; 1.1084x over previous
//
#include <hip/hip_runtime.h>

#define BN_EPS 1e-5f

typedef const float* fp;
typedef float f32x4 __attribute__((ext_vector_type(4)));
typedef _Float16 f16x2 __attribute__((ext_vector_type(2)));
typedef _Float16 f16x4 __attribute__((ext_vector_type(4)));
typedef _Float16 f16x8 __attribute__((ext_vector_type(8)));
typedef unsigned u32x4 __attribute__((ext_vector_type(4)));

// fast transcendentals: identical formulas to the previous (passing) kernel.
__device__ __forceinline__ float frcp(float x) { return __builtin_amdgcn_rcpf(x); }
__device__ __forceinline__ float sigm(float x) { return frcp(1.0f + __expf(-x)); }
__device__ __forceinline__ float tanh_fast(float x) { return 1.0f - 2.0f * frcp(1.0f + __expf(2.0f * x)); }

__device__ __forceinline__ f32x4 ld4(const float* p) { return *(const f32x4*)p; }
__device__ __forceinline__ float dot4(f32x4 a, f32x4 b) {
    return a[0] * b[0] + a[1] * b[1] + a[2] * b[2] + a[3] * b[3];
}

#define MFMA32(A, B, C) __builtin_amdgcn_mfma_f32_16x16x32_f16((A), (B), (C), 0, 0, 0)

// async global->LDS, 16B per lane; dest = uniform base + lane*16 (HW rule).
#define GLDS16(gp, lp) __builtin_amdgcn_global_load_lds( \
    (const __attribute__((address_space(1))) void*)(gp), \
    (__attribute__((address_space(3))) void*)(lp), 16, 0, 0)

// pack f32x4 -> f16x4 via v_cvt_pkrtz (2 inst).
__device__ __forceinline__ f16x4 pk_f16(f32x4 v) {
    f16x2 lo = __builtin_bit_cast(f16x2, __builtin_amdgcn_cvt_pkrtz(v[0], v[1]));
    f16x2 hi = __builtin_bit_cast(f16x2, __builtin_amdgcn_cvt_pkrtz(v[2], v[3]));
    return __builtin_shufflevector(lo, hi, 0, 1, 2, 3);
}

// ---------------------------------------------------------------------------
// K0: zero stats1[96] + stats2[32].
// ---------------------------------------------------------------------------
__global__ void k_zero(float* __restrict__ stats) { stats[threadIdx.x] = 0.f; }

// ---------------------------------------------------------------------------
// K2: MFMA GRU, 16 samples/wave (2048 waves, 2/SIMD — HW wave interleave
// beats in-wave ILP, proven R4/R11). 4-step unrolled loop over an 8-slot
// ring: ONE vmcnt(4) + ONE lgkmcnt(0) fence per 4 steps, ids via one
// ds_read_b128 per 4 steps, prefetch distance 7 steps. Iteration k consumes
// slots (4k..4k+3)&7 then restages the SAME slots for steps 4k+8..4k+11 =>
// WAR always against just-consumed slots. Tail drains with one vmcnt(0).
// Per-step math bit-identical to R10 (absmax 0.00390625). Requires T <= 52.
// ---------------------------------------------------------------------------
__device__ __forceinline__ void gru_step_mf(
    f32x4 e4,
    const f16x8& Ar, const f16x8& ArL, const f16x8& Az, const f16x8& AzL,
    const f16x8& Anx, const f16x8& Anh,
    const f32x4& br4, const f32x4& bz4, const f32x4& bxn4, const f32x4& bhn4,
    f32x4& h, f32x4& hsum, f16x4& hh)
{
    f16x4 e_h = pk_f16(e4);
    f16x8 Bhh = __builtin_shufflevector(e_h, hh, 0, 1, 2, 3, 4, 5, 6, 7);
    f16x8 Bee = __builtin_shufflevector(e_h, e_h, 0, 1, 2, 3, 0, 1, 2, 3);
    f16x8 Bh2 = __builtin_shufflevector(hh, hh, 0, 1, 2, 3, 0, 1, 2, 3);
    f32x4 aR = MFMA32(Ar, Bhh, MFMA32(ArL, Bhh, br4));
    f32x4 aZ = MFMA32(Az, Bhh, MFMA32(AzL, Bhh, bz4));
    f32x4 xn = MFMA32(Anx, Bee, bxn4);
    f32x4 hn = MFMA32(Anh, Bh2, bhn4);
    f32x4 r, z, nv;
#pragma unroll
    for (int q = 0; q < 4; ++q) { r[q] = sigm(aR[q]); z[q] = sigm(aZ[q]); }
    f32x4 pre = r * hn + xn;
#pragma unroll
    for (int q = 0; q < 4; ++q) nv[q] = tanh_fast(pre[q]);
    h = z * (h - nv) + nv;
    hsum += h;
    hh = pk_f16(h);
}

__global__ __launch_bounds__(256, 2) void k_gru(
    const int* __restrict__ user_id, const int* __restrict__ hist_item,
    const int* __restrict__ hist_cat, const int* __restrict__ tgt_item,
    const int* __restrict__ tgt_cat,
    fp user_table, fp item_table, fp cat_table,
    fp Whh, fp bhh, fp Wih, fp bih,
    fp mha_Win, fp mha_bin, fp mha_Wout, fp mha_bout,
    float* __restrict__ all_enc, float* __restrict__ stats1, int B, int T)
{
    __shared__ float    s_stage[4][8][256];   // 32KB [wave][slot][lane*4]
    __shared__ unsigned s_ids[4][16 * 68];    // 17.4KB packed (cd<<16)|id, stride 68
    __shared__ float    lds_part[4][96];

    const int tid  = threadIdx.x;
    const int lane = tid & 63;
    const int wid  = tid >> 6;
    const int s    = lane & 15;
    const int hi   = lane >> 4;

    long b = (long)blockIdx.x * 64 + wid * 16 + s;
    const bool act = (b < B);
    if (!act) b = B - 1;

    // epilogue indices: materialize before the barrier (VMEM retires there)
    const int ti  = tgt_item[b];
    const int tc  = tgt_cat[b];
    const int uid = user_id[b];
    asm volatile("" :: "v"(ti), "v"(tc), "v"(uid));

    const int T1 = T - 1;

    // one-time packed id preload into LDS, padded with clamped ids to idx 63
    {
        const int* ip = hist_item + b * T;
        const int* cp = hist_cat  + b * T;
        unsigned* d = &s_ids[wid][s * 68];
        for (int k = hi; k < 64; k += 4) {
            int src = (k <= T1) ? k : T1;
            d[k] = (unsigned)ip[src] | ((unsigned)cp[src] << 16);
        }
    }

    // ---- weight fragments + constant gate biases (one-time) ----
    f32x4 wirf = ld4(&Wih[(0  + s) * 16 + 4 * hi]);
    f32x4 wizf = ld4(&Wih[(16 + s) * 16 + 4 * hi]);
    f32x4 winf = ld4(&Wih[(32 + s) * 16 + 4 * hi]);
    f32x4 whrf = ld4(&Whh[(0  + s) * 16 + 4 * hi]);
    f32x4 whzf = ld4(&Whh[(16 + s) * 16 + 4 * hi]);
    f32x4 whnf = ld4(&Whh[(32 + s) * 16 + 4 * hi]);
    f16x4 wir_h = __builtin_convertvector(wirf, f16x4);
    f16x4 wiz_h = __builtin_convertvector(wizf, f16x4);
    f16x4 win_h = __builtin_convertvector(winf, f16x4);
    f16x4 whr_h = __builtin_convertvector(whrf, f16x4);
    f16x4 whz_h = __builtin_convertvector(whzf, f16x4);
    f16x4 whn_h = __builtin_convertvector(whnf, f16x4);
    f16x4 wir_l = __builtin_convertvector(wirf - __builtin_convertvector(wir_h, f32x4), f16x4);
    f16x4 wiz_l = __builtin_convertvector(wizf - __builtin_convertvector(wiz_h, f32x4), f16x4);
    f16x4 win_l = __builtin_convertvector(winf - __builtin_convertvector(win_h, f32x4), f16x4);
    f16x4 whr_l = __builtin_convertvector(whrf - __builtin_convertvector(whr_h, f32x4), f16x4);
    f16x4 whz_l = __builtin_convertvector(whzf - __builtin_convertvector(whz_h, f32x4), f16x4);
    f16x4 whn_l = __builtin_convertvector(whnf - __builtin_convertvector(whn_h, f32x4), f16x4);
    f16x8 Ar  = __builtin_shufflevector(wir_h, whr_h, 0, 1, 2, 3, 4, 5, 6, 7);
    f16x8 ArL = __builtin_shufflevector(wir_l, whr_l, 0, 1, 2, 3, 4, 5, 6, 7);
    f16x8 Az  = __builtin_shufflevector(wiz_h, whz_h, 0, 1, 2, 3, 4, 5, 6, 7);
    f16x8 AzL = __builtin_shufflevector(wiz_l, whz_l, 0, 1, 2, 3, 4, 5, 6, 7);
    f16x8 Anx = __builtin_shufflevector(win_h, win_l, 0, 1, 2, 3, 4, 5, 6, 7);
    f16x8 Anh = __builtin_shufflevector(whn_h, whn_l, 0, 1, 2, 3, 4, 5, 6, 7);
    const f32x4 br4  = ld4(&bih[4 * hi])      + ld4(&bhh[4 * hi]);
    const f32x4 bz4  = ld4(&bih[16 + 4 * hi]) + ld4(&bhh[16 + 4 * hi]);
    const f32x4 bxn4 = ld4(&bih[32 + 4 * hi]);
    const f32x4 bhn4 = ld4(&bhh[32 + 4 * hi]);

    f32x4 h = {0.f, 0.f, 0.f, 0.f}, hsum = {0.f, 0.f, 0.f, 0.f};
    f16x4 hh = {};

    __syncthreads();   // ids ready; all prologue VMEM drained here

    const unsigned* idsrow = &s_ids[wid][s * 68];
    float* stg = &s_stage[wid][0][0];
    const int l4 = lane * 4;

    // per-lane gather parameters
    const char*   gb   = (hi < 3) ? (const char*)item_table + hi * 16
                                  : (const char*)cat_table;
    const unsigned gsh  = (hi < 3) ? 0u : 16u;
    const unsigned gmul = (hi < 3) ? 48u : 16u;
#define GADDR(pk) (gb + (size_t)(((pk) >> gsh) & 0xffffu) * gmul)

    // prologue: stage slots 0..7 (steps 0..7, clamped); prefetch ids[8..11]
    {
        u32x4 i03 = *(const u32x4*)&idsrow[0];
        u32x4 i47 = *(const u32x4*)&idsrow[4];
        GLDS16(GADDR(i03[0]), stg);
        GLDS16(GADDR(i03[1]), stg + 256);
        GLDS16(GADDR(i03[2]), stg + 512);
        GLDS16(GADDR(i03[3]), stg + 768);
        GLDS16(GADDR(i47[0]), stg + 1024);
        GLDS16(GADDR(i47[1]), stg + 1280);
        GLDS16(GADDR(i47[2]), stg + 1536);
        GLDS16(GADDR(i47[3]), stg + 1792);
    }
    u32x4 idn = *(const u32x4*)&idsrow[8];

    const int M    = T >> 2;   // full 4-step iterations
    const int tail = T & 3;

    for (int k = 0; k < M; ++k) {
        const int base = k << 2;
        // oldest 4 of 8 outstanding retired => slots for steps base..base+3 landed
        asm volatile("s_waitcnt vmcnt(4)" ::: "memory");
        f32x4 e0 = ld4(stg + (((base + 0) & 7) << 8) + l4);
        f32x4 e1 = ld4(stg + (((base + 1) & 7) << 8) + l4);
        f32x4 e2 = ld4(stg + (((base + 2) & 7) << 8) + l4);
        f32x4 e3 = ld4(stg + (((base + 3) & 7) << 8) + l4);
        u32x4 idc = idn;
        idn = *(const u32x4*)&idsrow[base + 12];   // for next iteration

        gru_step_mf(e0, Ar, ArL, Az, AzL, Anx, Anh, br4, bz4, bxn4, bhn4, h, hsum, hh);
        gru_step_mf(e1, Ar, ArL, Az, AzL, Anx, Anh, br4, bz4, bxn4, bhn4, h, hsum, hh);
        gru_step_mf(e2, Ar, ArL, Az, AzL, Anx, Anh, br4, bz4, bxn4, bhn4, h, hsum, hh);
        gru_step_mf(e3, Ar, ArL, Az, AzL, Anx, Anh, br4, bz4, bxn4, bhn4, h, hsum, hh);

        // DS reads above long retired (free) — clears WAR for re-staging
        asm volatile("s_waitcnt lgkmcnt(0)" ::: "memory");
        GLDS16(GADDR(idc[0]), stg + (((base + 0) & 7) << 8));   // step base+8
        GLDS16(GADDR(idc[1]), stg + (((base + 1) & 7) << 8));   // step base+9
        GLDS16(GADDR(idc[2]), stg + (((base + 2) & 7) << 8));   // step base+10
        GLDS16(GADDR(idc[3]), stg + (((base + 3) & 7) << 8));   // step base+11
    }
    if (tail) {
        asm volatile("s_waitcnt vmcnt(0)" ::: "memory");
        for (int t = M << 2; t < T; ++t) {
            f32x4 e = ld4(stg + ((t & 7) << 8) + l4);
            gru_step_mf(e, Ar, ArL, Az, AzL, Anx, Anh, br4, bz4, bxn4, bhn4, h, hsum, hh);
        }
    }

    // ---- epilogue: degenerate MHA -> A[b], all_enc row, BN1 stats ----
    const float* itr = item_table + (size_t)ti * 12;
    f32x4 tv0 = ld4(itr), tv1 = ld4(itr + 4), tv2 = ld4(itr + 8);
    f32x4 tv3 = ld4(cat_table + tc * 4);

    f32x4 vq;
#pragma unroll
    for (int q = 0; q < 4; ++q) {
        int row = 32 + 4 * hi + q;
        const float* wv = mha_Win + row * 16;
        vq[q] = mha_bin[row] + dot4(ld4(wv), tv0) + dot4(ld4(wv + 4), tv1)
              + dot4(ld4(wv + 8), tv2) + dot4(ld4(wv + 12), tv3);
    }
    f32x4 vg0, vg1, vg2, vg3;
#pragma unroll
    for (int q = 0; q < 4; ++q) {
        vg0[q] = __shfl_xor(vq[q], (hi ^ 0) << 4);
        vg1[q] = __shfl_xor(vq[q], (hi ^ 1) << 4);
        vg2[q] = __shfl_xor(vq[q], (hi ^ 2) << 4);
        vg3[q] = __shfl_xor(vq[q], (hi ^ 3) << 4);
    }
    f32x4 aj;
#pragma unroll
    for (int q = 0; q < 4; ++q) {
        int row = 4 * hi + q;
        const float* wo = mha_Wout + row * 16;
        aj[q] = mha_bout[row] + dot4(ld4(wo), vg0) + dot4(ld4(wo + 4), vg1)
              + dot4(ld4(wo + 8), vg2) + dot4(ld4(wo + 12), vg3);
    }
    f32x4 avg = aj * hsum;

    f32x4 u4  = ld4(user_table + (size_t)uid * 16 + 4 * hi);
    f32x4 t4v = (hi == 0) ? tv0 : (hi == 1) ? tv1 : (hi == 2) ? tv2 : tv3;

    if (act) {
        float* er = all_enc + b * 48 + 4 * hi;
        *(f32x4*)er        = avg;
        *(f32x4*)(er + 16) = t4v;
        *(f32x4*)(er + 32) = u4;
    }

    const f32x4 zero4 = {0.f, 0.f, 0.f, 0.f};
    f32x4 sa = act ? avg : zero4, st = act ? t4v : zero4, su = act ? u4 : zero4;
    f32x4 qa = sa * sa, qt = st * st, qu = su * su;
#pragma unroll
    for (int m = 1; m <= 8; m <<= 1) {
#pragma unroll
        for (int q = 0; q < 4; ++q) {
            sa[q] += __shfl_xor(sa[q], m);
            st[q] += __shfl_xor(st[q], m);
            su[q] += __shfl_xor(su[q], m);
            qa[q] += __shfl_xor(qa[q], m);
            qt[q] += __shfl_xor(qt[q], m);
            qu[q] += __shfl_xor(qu[q], m);
        }
    }
    if (s == 0) {
        int c = 4 * hi;
#pragma unroll
        for (int q = 0; q < 4; ++q) {
            lds_part[wid][c + q]      = sa[q];
            lds_part[wid][16 + c + q] = st[q];
            lds_part[wid][32 + c + q] = su[q];
            lds_part[wid][48 + c + q] = qa[q];
            lds_part[wid][64 + c + q] = qt[q];
            lds_part[wid][80 + c + q] = qu[q];
        }
    }
    __syncthreads();
    if (tid < 96) {
        float v = lds_part[0][tid] + lds_part[1][tid] + lds_part[2][tid] + lds_part[3][tid];
        atomicAdd(&stats1[tid], v);
    }
}

// ---------------------------------------------------------------------------
// K3: fc1 with BN1-fold computed inline per block (512 blocks — the 1024
// variant regressed: doubled fold/weight prologue + stats2 atomic pressure).
// ---------------------------------------------------------------------------
__global__ __launch_bounds__(256) void k_fc1(
    const float* __restrict__ all_enc, const float* __restrict__ stats,
    fp fc1_W, fp fc1_b, fp g1, fp b1,
    float* __restrict__ hbuf, float* __restrict__ stats2, int B)
{
    const int tid = threadIdx.x, lane = tid & 63, wid = tid >> 6;
    const int j = lane & 15, sl = lane >> 4;
    __shared__ float kk[48], mm[48];
    __shared__ float part[4][32];

    if (tid < 48) {
        float mu  = stats[tid] / (float)B;
        float var = stats[48 + tid] / (float)B - mu * mu;
        float k   = rsqrtf(var + BN_EPS);
        float gk  = g1[tid] * k;
        kk[tid] = gk;
        mm[tid] = b1[tid] - mu * gk;
    }
    __syncthreads();

    float w[48];
    float bj = fc1_b[j];
#pragma unroll
    for (int q = 0; q < 12; ++q) {
        float4 v = *(const float4*)&fc1_W[j * 48 + q * 4];
        w[q * 4 + 0] = v.x * kk[q * 4 + 0];
        w[q * 4 + 1] = v.y * kk[q * 4 + 1];
        w[q * 4 + 2] = v.z * kk[q * 4 + 2];
        w[q * 4 + 3] = v.w * kk[q * 4 + 3];
        bj += v.x * mm[q * 4 + 0] + v.y * mm[q * 4 + 1]
            + v.z * mm[q * 4 + 2] + v.w * mm[q * 4 + 3];
    }

    float sh = 0.f, sq = 0.f;
    for (long b = (long)blockIdx.x * 16 + wid * 4 + sl; b < B; b += (long)gridDim.x * 16) {
        const float* x = all_enc + b * 48;
        float acc = bj;
#pragma unroll
        for (int q = 0; q < 12; ++q) {
            float4 v = *(const float4*)&x[q * 4];
            acc += w[q * 4] * v.x + w[q * 4 + 1] * v.y + w[q * 4 + 2] * v.z + w[q * 4 + 3] * v.w;
        }
        float h = fmaxf(acc, 0.f);
        hbuf[b * 16 + j] = h;
        sh += h; sq += h * h;
    }
    sh += __shfl_xor(sh, 16); sh += __shfl_xor(sh, 32);
    sq += __shfl_xor(sq, 16); sq += __shfl_xor(sq, 32);
    if (sl == 0) { part[wid][j] = sh; part[wid][16 + j] = sq; }
    __syncthreads();
    if (tid < 32) {
        float v = part[0][tid] + part[1][tid] + part[2][tid] + part[3][tid];
        atomicAdd(&stats2[tid], v);
    }
}

// ---------------------------------------------------------------------------
// K4: logits + softmax, BN2-fold computed inline per block.
// ---------------------------------------------------------------------------
__global__ __launch_bounds__(256) void k_out(
    const float* __restrict__ hbuf, const float* __restrict__ stats2,
    fp fc2_W, fp fc2_b, fp g2, fp b2, float* __restrict__ out, int B)
{
    __shared__ float w[34];
    const int tid = threadIdx.x;
    if (tid < 32) {
        int c = tid & 15;
        float mu  = stats2[c] / (float)B;
        float var = stats2[16 + c] / (float)B - mu * mu;
        float gk  = g2[c] * rsqrtf(var + BN_EPS);
        w[tid] = fc2_W[tid] * gk;
    }
    if (tid < 2) {
        float acc = fc2_b[tid];
        for (int c = 0; c < 16; ++c) {
            float mu  = stats2[c] / (float)B;
            float var = stats2[16 + c] / (float)B - mu * mu;
            float gk  = g2[c] * rsqrtf(var + BN_EPS);
            acc += fc2_W[tid * 16 + c] * (b2[c] - mu * gk);
        }
        w[32 + tid] = acc;
    }
    __syncthreads();
    for (long b = (long)blockIdx.x * blockDim.x + threadIdx.x; b < B;
         b += (long)gridDim.x * blockDim.x) {
        const float* h = hbuf + b * 16;
        float l0 = w[32], l1 = w[33];
#pragma unroll
        for (int q = 0; q < 4; ++q) {
            float4 v = *(const float4*)&h[q * 4];
            l0 += w[q * 4] * v.x + w[q * 4 + 1] * v.y + w[q * 4 + 2] * v.z + w[q * 4 + 3] * v.w;
            l1 += w[16 + q * 4] * v.x + w[17 + q * 4] * v.y + w[18 + q * 4] * v.z + w[19 + q * 4] * v.w;
        }
        float m  = fmaxf(l0, l1);
        float e0 = __expf(l0 - m), e1 = __expf(l1 - m);
        float inv = frcp(e0 + e1);
        float2 p; p.x = e0 * inv; p.y = e1 * inv;
        *(float2*)&out[b * 2] = p;
    }
}

// ---------------------------------------------------------------------------
extern "C" void kernel_launch(void* const* d_in, const int* in_sizes, int n_in,
                              void* d_out, int out_size, void* d_ws, size_t ws_size,
                              hipStream_t stream)
{
    const int* user_id   = (const int*)d_in[0];
    const int* hist_item = (const int*)d_in[1];
    const int* hist_cat  = (const int*)d_in[2];
    const int* tgt_item  = (const int*)d_in[3];
    const int* tgt_cat   = (const int*)d_in[4];
    fp user_table = (fp)d_in[5];
    fp item_table = (fp)d_in[6];
    fp cat_table  = (fp)d_in[7];
    fp Wih = (fp)d_in[8],  Whh = (fp)d_in[9];
    fp bih = (fp)d_in[10], bhh = (fp)d_in[11];
    fp Win = (fp)d_in[12], binp = (fp)d_in[13];
    fp Wout = (fp)d_in[14], bout = (fp)d_in[15];
    fp g1 = (fp)d_in[16], b1 = (fp)d_in[17];
    fp fc1W = (fp)d_in[18], fc1b = (fp)d_in[19];
    fp g2 = (fp)d_in[20], b2 = (fp)d_in[21];
    fp fc2W = (fp)d_in[22], fc2b = (fp)d_in[23];

    const int B = in_sizes[0];
    const int T = in_sizes[1] / B;

    float* ws       = (float*)d_ws;
    float* stats1   = ws;                       // 96
    float* stats2   = ws + 96;                  // 32
    float* all_enc  = ws + 128;                 // B*48 (16B aligned)
    float* hbuf     = all_enc + (size_t)B * 48; // B*16

    hipLaunchKernelGGL(k_zero, dim3(1), dim3(128), 0, stream, ws);

    hipLaunchKernelGGL(k_gru, dim3((B + 63) / 64), dim3(256), 0, stream,
                       user_id, hist_item, hist_cat, tgt_item, tgt_cat,
                       user_table, item_table, cat_table, Whh, bhh, Wih, bih,
                       Win, binp, Wout, bout, all_enc, stats1, B, T);

    hipLaunchKernelGGL(k_fc1, dim3(512), dim3(256), 0, stream,
                       all_enc, stats1, fc1W, fc1b, g1, b1, hbuf, stats2, B);

    hipLaunchKernelGGL(k_out, dim3((B + 255) / 256), dim3(256), 0, stream,
                       hbuf, stats2, fc2W, fc2b, g2, b2, (float*)d_out, B);
}

// Round 14
// 63.819 us; speedup vs baseline: 1.1191x; 1.0015x over previous
//
#include <hip/hip_runtime.h>

#define BN_EPS 1e-5f

typedef const float* fp;
typedef float f32x4 __attribute__((ext_vector_type(4)));
typedef _Float16 f16x2 __attribute__((ext_vector_type(2)));
typedef _Float16 f16x4 __attribute__((ext_vector_type(4)));
typedef _Float16 f16x8 __attribute__((ext_vector_type(8)));
typedef unsigned u32x4 __attribute__((ext_vector_type(4)));

// fast transcendentals: identical formulas to the previous (passing) kernel.
__device__ __forceinline__ float frcp(float x) { return __builtin_amdgcn_rcpf(x); }
__device__ __forceinline__ float sigm(float x) { return frcp(1.0f + __expf(-x)); }
__device__ __forceinline__ float tanh_fast(float x) { return 1.0f - 2.0f * frcp(1.0f + __expf(2.0f * x)); }

__device__ __forceinline__ f32x4 ld4(const float* p) { return *(const f32x4*)p; }
__device__ __forceinline__ float dot4(f32x4 a, f32x4 b) {
    return a[0] * b[0] + a[1] * b[1] + a[2] * b[2] + a[3] * b[3];
}

#define MFMA32(A, B, C) __builtin_amdgcn_mfma_f32_16x16x32_f16((A), (B), (C), 0, 0, 0)

// async global->LDS, 16B per lane; dest = uniform base + lane*16 (HW rule).
#define GLDS16(gp, lp) __builtin_amdgcn_global_load_lds( \
    (const __attribute__((address_space(1))) void*)(gp), \
    (__attribute__((address_space(3))) void*)(lp), 16, 0, 0)

// pack f32x4 -> f16x4 via v_cvt_pkrtz (2 inst).
__device__ __forceinline__ f16x4 pk_f16(f32x4 v) {
    f16x2 lo = __builtin_bit_cast(f16x2, __builtin_amdgcn_cvt_pkrtz(v[0], v[1]));
    f16x2 hi = __builtin_bit_cast(f16x2, __builtin_amdgcn_cvt_pkrtz(v[2], v[3]));
    return __builtin_shufflevector(lo, hi, 0, 1, 2, 3);
}

// ---------------------------------------------------------------------------
// K0: zero stats1[96] + stats2[32].
// ---------------------------------------------------------------------------
__global__ void k_zero(float* __restrict__ stats) { stats[threadIdx.x] = 0.f; }

// ---------------------------------------------------------------------------
// K2: MFMA GRU, 16 samples/wave, 4-step unrolled 8-slot ring (R13 skeleton).
// NEW: e/h gate split. The e-dependent halves of r,z (and all of xn) are
// h-INDEPENDENT: xg_i = MFMA([Wih_hi|Wih_lo], [e_i|e_i], bias) — hoisted for
// all 4 steps of the block right after the ds_reads (12 independent MFMAs +
// 4 pk_f16 = fill work from the SAME samples' future inputs; no extra
// architectural state, unlike the failed 2-chain R11). The dependent part
// per step is now ONE MFMA per gate: aG = MFMA([Whh_hi|Whh_lo],[h|h],xg).
// Same 6 MFMAs/step, same term set (accumulation order only). absmax must
// stay 0.00390625. Requires T <= 52.
// ---------------------------------------------------------------------------
__device__ __forceinline__ void gru_step_h(
    f32x4 xr, f32x4 xz, f32x4 xn,
    const f16x8& Ahr, const f16x8& Ahz, const f16x8& Ahn, const f32x4& bhn4,
    f32x4& h, f32x4& hsum, f16x4& hh)
{
    f16x8 Bh2 = __builtin_shufflevector(hh, hh, 0, 1, 2, 3, 0, 1, 2, 3);
    f32x4 aR = MFMA32(Ahr, Bh2, xr);
    f32x4 aZ = MFMA32(Ahz, Bh2, xz);
    f32x4 hn = MFMA32(Ahn, Bh2, bhn4);
    f32x4 r, z, nv;
#pragma unroll
    for (int q = 0; q < 4; ++q) { r[q] = sigm(aR[q]); z[q] = sigm(aZ[q]); }
    f32x4 pre = r * hn + xn;
#pragma unroll
    for (int q = 0; q < 4; ++q) nv[q] = tanh_fast(pre[q]);
    h = z * (h - nv) + nv;
    hsum += h;
    hh = pk_f16(h);
}

__global__ __launch_bounds__(256, 2) void k_gru(
    const int* __restrict__ user_id, const int* __restrict__ hist_item,
    const int* __restrict__ hist_cat, const int* __restrict__ tgt_item,
    const int* __restrict__ tgt_cat,
    fp user_table, fp item_table, fp cat_table,
    fp Whh, fp bhh, fp Wih, fp bih,
    fp mha_Win, fp mha_bin, fp mha_Wout, fp mha_bout,
    float* __restrict__ all_enc, float* __restrict__ stats1, int B, int T)
{
    __shared__ float    s_stage[4][8][256];   // 32KB [wave][slot][lane*4]
    __shared__ unsigned s_ids[4][16 * 68];    // 17.4KB packed (cd<<16)|id, stride 68
    __shared__ float    lds_part[4][96];

    const int tid  = threadIdx.x;
    const int lane = tid & 63;
    const int wid  = tid >> 6;
    const int s    = lane & 15;
    const int hi   = lane >> 4;

    long b = (long)blockIdx.x * 64 + wid * 16 + s;
    const bool act = (b < B);
    if (!act) b = B - 1;

    // epilogue indices: materialize before the barrier (VMEM retires there)
    const int ti  = tgt_item[b];
    const int tc  = tgt_cat[b];
    const int uid = user_id[b];
    asm volatile("" :: "v"(ti), "v"(tc), "v"(uid));

    const int T1 = T - 1;

    // one-time packed id preload into LDS, padded with clamped ids to idx 63
    {
        const int* ip = hist_item + b * T;
        const int* cp = hist_cat  + b * T;
        unsigned* d = &s_ids[wid][s * 68];
        for (int k = hi; k < 64; k += 4) {
            int src = (k <= T1) ? k : T1;
            d[k] = (unsigned)ip[src] | ((unsigned)cp[src] << 16);
        }
    }

    // ---- weight fragments + constant gate biases (one-time) ----
    f32x4 wirf = ld4(&Wih[(0  + s) * 16 + 4 * hi]);
    f32x4 wizf = ld4(&Wih[(16 + s) * 16 + 4 * hi]);
    f32x4 winf = ld4(&Wih[(32 + s) * 16 + 4 * hi]);
    f32x4 whrf = ld4(&Whh[(0  + s) * 16 + 4 * hi]);
    f32x4 whzf = ld4(&Whh[(16 + s) * 16 + 4 * hi]);
    f32x4 whnf = ld4(&Whh[(32 + s) * 16 + 4 * hi]);
    f16x4 wir_h = __builtin_convertvector(wirf, f16x4);
    f16x4 wiz_h = __builtin_convertvector(wizf, f16x4);
    f16x4 win_h = __builtin_convertvector(winf, f16x4);
    f16x4 whr_h = __builtin_convertvector(whrf, f16x4);
    f16x4 whz_h = __builtin_convertvector(whzf, f16x4);
    f16x4 whn_h = __builtin_convertvector(whnf, f16x4);
    f16x4 wir_l = __builtin_convertvector(wirf - __builtin_convertvector(wir_h, f32x4), f16x4);
    f16x4 wiz_l = __builtin_convertvector(wizf - __builtin_convertvector(wiz_h, f32x4), f16x4);
    f16x4 win_l = __builtin_convertvector(winf - __builtin_convertvector(win_h, f32x4), f16x4);
    f16x4 whr_l = __builtin_convertvector(whrf - __builtin_convertvector(whr_h, f32x4), f16x4);
    f16x4 whz_l = __builtin_convertvector(whzf - __builtin_convertvector(whz_h, f32x4), f16x4);
    f16x4 whn_l = __builtin_convertvector(whnf - __builtin_convertvector(whn_h, f32x4), f16x4);
    // input-side A-frags [Wih_hi|Wih_lo], recurrent-side A-frags [Whh_hi|Whh_lo]
    f16x8 Air = __builtin_shufflevector(wir_h, wir_l, 0, 1, 2, 3, 4, 5, 6, 7);
    f16x8 Aiz = __builtin_shufflevector(wiz_h, wiz_l, 0, 1, 2, 3, 4, 5, 6, 7);
    f16x8 Ain = __builtin_shufflevector(win_h, win_l, 0, 1, 2, 3, 4, 5, 6, 7);
    f16x8 Ahr = __builtin_shufflevector(whr_h, whr_l, 0, 1, 2, 3, 4, 5, 6, 7);
    f16x8 Ahz = __builtin_shufflevector(whz_h, whz_l, 0, 1, 2, 3, 4, 5, 6, 7);
    f16x8 Ahn = __builtin_shufflevector(whn_h, whn_l, 0, 1, 2, 3, 4, 5, 6, 7);
    const f32x4 br4  = ld4(&bih[4 * hi])      + ld4(&bhh[4 * hi]);
    const f32x4 bz4  = ld4(&bih[16 + 4 * hi]) + ld4(&bhh[16 + 4 * hi]);
    const f32x4 bxn4 = ld4(&bih[32 + 4 * hi]);
    const f32x4 bhn4 = ld4(&bhh[32 + 4 * hi]);

    f32x4 h = {0.f, 0.f, 0.f, 0.f}, hsum = {0.f, 0.f, 0.f, 0.f};
    f16x4 hh = {};

    __syncthreads();   // ids ready; all prologue VMEM drained here

    const unsigned* idsrow = &s_ids[wid][s * 68];
    float* stg = &s_stage[wid][0][0];
    const int l4 = lane * 4;

    // per-lane gather parameters
    const char*   gb   = (hi < 3) ? (const char*)item_table + hi * 16
                                  : (const char*)cat_table;
    const unsigned gsh  = (hi < 3) ? 0u : 16u;
    const unsigned gmul = (hi < 3) ? 48u : 16u;
#define GADDR(pk) (gb + (size_t)(((pk) >> gsh) & 0xffffu) * gmul)

    // prologue: stage slots 0..7 (steps 0..7, clamped); prefetch ids[8..11]
    {
        u32x4 i03 = *(const u32x4*)&idsrow[0];
        u32x4 i47 = *(const u32x4*)&idsrow[4];
        GLDS16(GADDR(i03[0]), stg);
        GLDS16(GADDR(i03[1]), stg + 256);
        GLDS16(GADDR(i03[2]), stg + 512);
        GLDS16(GADDR(i03[3]), stg + 768);
        GLDS16(GADDR(i47[0]), stg + 1024);
        GLDS16(GADDR(i47[1]), stg + 1280);
        GLDS16(GADDR(i47[2]), stg + 1536);
        GLDS16(GADDR(i47[3]), stg + 1792);
    }
    u32x4 idn = *(const u32x4*)&idsrow[8];

    const int M    = T >> 2;   // full 4-step iterations
    const int tail = T & 3;

    for (int k = 0; k < M; ++k) {
        const int base = k << 2;
        // oldest 4 of 8 outstanding retired => slots for steps base..base+3 landed
        asm volatile("s_waitcnt vmcnt(4)" ::: "memory");
        f32x4 e0 = ld4(stg + (((base + 0) & 7) << 8) + l4);
        f32x4 e1 = ld4(stg + (((base + 1) & 7) << 8) + l4);
        f32x4 e2 = ld4(stg + (((base + 2) & 7) << 8) + l4);
        f32x4 e3 = ld4(stg + (((base + 3) & 7) << 8) + l4);
        u32x4 idc = idn;
        idn = *(const u32x4*)&idsrow[base + 12];   // for next iteration

        // ---- h-independent e-side MFMAs for all 4 steps (fill work) ----
        f16x4 eh0 = pk_f16(e0);
        f16x4 eh1 = pk_f16(e1);
        f16x4 eh2 = pk_f16(e2);
        f16x4 eh3 = pk_f16(e3);
        f16x8 Be0 = __builtin_shufflevector(eh0, eh0, 0, 1, 2, 3, 0, 1, 2, 3);
        f16x8 Be1 = __builtin_shufflevector(eh1, eh1, 0, 1, 2, 3, 0, 1, 2, 3);
        f16x8 Be2 = __builtin_shufflevector(eh2, eh2, 0, 1, 2, 3, 0, 1, 2, 3);
        f16x8 Be3 = __builtin_shufflevector(eh3, eh3, 0, 1, 2, 3, 0, 1, 2, 3);
        f32x4 xr0 = MFMA32(Air, Be0, br4),  xz0 = MFMA32(Aiz, Be0, bz4),  xn0 = MFMA32(Ain, Be0, bxn4);
        f32x4 xr1 = MFMA32(Air, Be1, br4),  xz1 = MFMA32(Aiz, Be1, bz4),  xn1 = MFMA32(Ain, Be1, bxn4);
        f32x4 xr2 = MFMA32(Air, Be2, br4),  xz2 = MFMA32(Aiz, Be2, bz4),  xn2 = MFMA32(Ain, Be2, bxn4);
        f32x4 xr3 = MFMA32(Air, Be3, br4),  xz3 = MFMA32(Aiz, Be3, bz4),  xn3 = MFMA32(Ain, Be3, bxn4);

        // ---- dependent recurrence: ONE MFMA per gate per step ----
        gru_step_h(xr0, xz0, xn0, Ahr, Ahz, Ahn, bhn4, h, hsum, hh);
        gru_step_h(xr1, xz1, xn1, Ahr, Ahz, Ahn, bhn4, h, hsum, hh);
        gru_step_h(xr2, xz2, xn2, Ahr, Ahz, Ahn, bhn4, h, hsum, hh);
        gru_step_h(xr3, xz3, xn3, Ahr, Ahz, Ahn, bhn4, h, hsum, hh);

        // DS reads above long retired (free) — clears WAR for re-staging
        asm volatile("s_waitcnt lgkmcnt(0)" ::: "memory");
        GLDS16(GADDR(idc[0]), stg + (((base + 0) & 7) << 8));   // step base+8
        GLDS16(GADDR(idc[1]), stg + (((base + 1) & 7) << 8));   // step base+9
        GLDS16(GADDR(idc[2]), stg + (((base + 2) & 7) << 8));   // step base+10
        GLDS16(GADDR(idc[3]), stg + (((base + 3) & 7) << 8));   // step base+11
    }
    if (tail) {
        asm volatile("s_waitcnt vmcnt(0)" ::: "memory");
        for (int t = M << 2; t < T; ++t) {
            f32x4 e = ld4(stg + ((t & 7) << 8) + l4);
            f16x4 eh = pk_f16(e);
            f16x8 Be = __builtin_shufflevector(eh, eh, 0, 1, 2, 3, 0, 1, 2, 3);
            f32x4 xr = MFMA32(Air, Be, br4);
            f32x4 xz = MFMA32(Aiz, Be, bz4);
            f32x4 xn = MFMA32(Ain, Be, bxn4);
            gru_step_h(xr, xz, xn, Ahr, Ahz, Ahn, bhn4, h, hsum, hh);
        }
    }

    // ---- epilogue: degenerate MHA -> A[b], all_enc row, BN1 stats ----
    const float* itr = item_table + (size_t)ti * 12;
    f32x4 tv0 = ld4(itr), tv1 = ld4(itr + 4), tv2 = ld4(itr + 8);
    f32x4 tv3 = ld4(cat_table + tc * 4);

    f32x4 vq;
#pragma unroll
    for (int q = 0; q < 4; ++q) {
        int row = 32 + 4 * hi + q;
        const float* wv = mha_Win + row * 16;
        vq[q] = mha_bin[row] + dot4(ld4(wv), tv0) + dot4(ld4(wv + 4), tv1)
              + dot4(ld4(wv + 8), tv2) + dot4(ld4(wv + 12), tv3);
    }
    f32x4 vg0, vg1, vg2, vg3;
#pragma unroll
    for (int q = 0; q < 4; ++q) {
        vg0[q] = __shfl_xor(vq[q], (hi ^ 0) << 4);
        vg1[q] = __shfl_xor(vq[q], (hi ^ 1) << 4);
        vg2[q] = __shfl_xor(vq[q], (hi ^ 2) << 4);
        vg3[q] = __shfl_xor(vq[q], (hi ^ 3) << 4);
    }
    f32x4 aj;
#pragma unroll
    for (int q = 0; q < 4; ++q) {
        int row = 4 * hi + q;
        const float* wo = mha_Wout + row * 16;
        aj[q] = mha_bout[row] + dot4(ld4(wo), vg0) + dot4(ld4(wo + 4), vg1)
              + dot4(ld4(wo + 8), vg2) + dot4(ld4(wo + 12), vg3);
    }
    f32x4 avg = aj * hsum;

    f32x4 u4  = ld4(user_table + (size_t)uid * 16 + 4 * hi);
    f32x4 t4v = (hi == 0) ? tv0 : (hi == 1) ? tv1 : (hi == 2) ? tv2 : tv3;

    if (act) {
        float* er = all_enc + b * 48 + 4 * hi;
        *(f32x4*)er        = avg;
        *(f32x4*)(er + 16) = t4v;
        *(f32x4*)(er + 32) = u4;
    }

    const f32x4 zero4 = {0.f, 0.f, 0.f, 0.f};
    f32x4 sa = act ? avg : zero4, st = act ? t4v : zero4, su = act ? u4 : zero4;
    f32x4 qa = sa * sa, qt = st * st, qu = su * su;
#pragma unroll
    for (int m = 1; m <= 8; m <<= 1) {
#pragma unroll
        for (int q = 0; q < 4; ++q) {
            sa[q] += __shfl_xor(sa[q], m);
            st[q] += __shfl_xor(st[q], m);
            su[q] += __shfl_xor(su[q], m);
            qa[q] += __shfl_xor(qa[q], m);
            qt[q] += __shfl_xor(qt[q], m);
            qu[q] += __shfl_xor(qu[q], m);
        }
    }
    if (s == 0) {
        int c = 4 * hi;
#pragma unroll
        for (int q = 0; q < 4; ++q) {
            lds_part[wid][c + q]      = sa[q];
            lds_part[wid][16 + c + q] = st[q];
            lds_part[wid][32 + c + q] = su[q];
            lds_part[wid][48 + c + q] = qa[q];
            lds_part[wid][64 + c + q] = qt[q];
            lds_part[wid][80 + c + q] = qu[q];
        }
    }
    __syncthreads();
    if (tid < 96) {
        float v = lds_part[0][tid] + lds_part[1][tid] + lds_part[2][tid] + lds_part[3][tid];
        atomicAdd(&stats1[tid], v);
    }
}

// ---------------------------------------------------------------------------
// K3: fc1 with BN1-fold computed inline per block (512 blocks).
// ---------------------------------------------------------------------------
__global__ __launch_bounds__(256) void k_fc1(
    const float* __restrict__ all_enc, const float* __restrict__ stats,
    fp fc1_W, fp fc1_b, fp g1, fp b1,
    float* __restrict__ hbuf, float* __restrict__ stats2, int B)
{
    const int tid = threadIdx.x, lane = tid & 63, wid = tid >> 6;
    const int j = lane & 15, sl = lane >> 4;
    __shared__ float kk[48], mm[48];
    __shared__ float part[4][32];

    if (tid < 48) {
        float mu  = stats[tid] / (float)B;
        float var = stats[48 + tid] / (float)B - mu * mu;
        float k   = rsqrtf(var + BN_EPS);
        float gk  = g1[tid] * k;
        kk[tid] = gk;
        mm[tid] = b1[tid] - mu * gk;
    }
    __syncthreads();

    float w[48];
    float bj = fc1_b[j];
#pragma unroll
    for (int q = 0; q < 12; ++q) {
        float4 v = *(const float4*)&fc1_W[j * 48 + q * 4];
        w[q * 4 + 0] = v.x * kk[q * 4 + 0];
        w[q * 4 + 1] = v.y * kk[q * 4 + 1];
        w[q * 4 + 2] = v.z * kk[q * 4 + 2];
        w[q * 4 + 3] = v.w * kk[q * 4 + 3];
        bj += v.x * mm[q * 4 + 0] + v.y * mm[q * 4 + 1]
            + v.z * mm[q * 4 + 2] + v.w * mm[q * 4 + 3];
    }

    float sh = 0.f, sq = 0.f;
    for (long b = (long)blockIdx.x * 16 + wid * 4 + sl; b < B; b += (long)gridDim.x * 16) {
        const float* x = all_enc + b * 48;
        float acc = bj;
#pragma unroll
        for (int q = 0; q < 12; ++q) {
            float4 v = *(const float4*)&x[q * 4];
            acc += w[q * 4] * v.x + w[q * 4 + 1] * v.y + w[q * 4 + 2] * v.z + w[q * 4 + 3] * v.w;
        }
        float h = fmaxf(acc, 0.f);
        hbuf[b * 16 + j] = h;
        sh += h; sq += h * h;
    }
    sh += __shfl_xor(sh, 16); sh += __shfl_xor(sh, 32);
    sq += __shfl_xor(sq, 16); sq += __shfl_xor(sq, 32);
    if (sl == 0) { part[wid][j] = sh; part[wid][16 + j] = sq; }
    __syncthreads();
    if (tid < 32) {
        float v = part[0][tid] + part[1][tid] + part[2][tid] + part[3][tid];
        atomicAdd(&stats2[tid], v);
    }
}

// ---------------------------------------------------------------------------
// K4: logits + softmax, BN2-fold computed inline per block.
// ---------------------------------------------------------------------------
__global__ __launch_bounds__(256) void k_out(
    const float* __restrict__ hbuf, const float* __restrict__ stats2,
    fp fc2_W, fp fc2_b, fp g2, fp b2, float* __restrict__ out, int B)
{
    __shared__ float w[34];
    const int tid = threadIdx.x;
    if (tid < 32) {
        int c = tid & 15;
        float mu  = stats2[c] / (float)B;
        float var = stats2[16 + c] / (float)B - mu * mu;
        float gk  = g2[c] * rsqrtf(var + BN_EPS);
        w[tid] = fc2_W[tid] * gk;
    }
    if (tid < 2) {
        float acc = fc2_b[tid];
        for (int c = 0; c < 16; ++c) {
            float mu  = stats2[c] / (float)B;
            float var = stats2[16 + c] / (float)B - mu * mu;
            float gk  = g2[c] * rsqrtf(var + BN_EPS);
            acc += fc2_W[tid * 16 + c] * (b2[c] - mu * gk);
        }
        w[32 + tid] = acc;
    }
    __syncthreads();
    for (long b = (long)blockIdx.x * blockDim.x + threadIdx.x; b < B;
         b += (long)gridDim.x * blockDim.x) {
        const float* h = hbuf + b * 16;
        float l0 = w[32], l1 = w[33];
#pragma unroll
        for (int q = 0; q < 4; ++q) {
            float4 v = *(const float4*)&h[q * 4];
            l0 += w[q * 4] * v.x + w[q * 4 + 1] * v.y + w[q * 4 + 2] * v.z + w[q * 4 + 3] * v.w;
            l1 += w[16 + q * 4] * v.x + w[17 + q * 4] * v.y + w[18 + q * 4] * v.z + w[19 + q * 4] * v.w;
        }
        float m  = fmaxf(l0, l1);
        float e0 = __expf(l0 - m), e1 = __expf(l1 - m);
        float inv = frcp(e0 + e1);
        float2 p; p.x = e0 * inv; p.y = e1 * inv;
        *(float2*)&out[b * 2] = p;
    }
}

// ---------------------------------------------------------------------------
extern "C" void kernel_launch(void* const* d_in, const int* in_sizes, int n_in,
                              void* d_out, int out_size, void* d_ws, size_t ws_size,
                              hipStream_t stream)
{
    const int* user_id   = (const int*)d_in[0];
    const int* hist_item = (const int*)d_in[1];
    const int* hist_cat  = (const int*)d_in[2];
    const int* tgt_item  = (const int*)d_in[3];
    const int* tgt_cat   = (const int*)d_in[4];
    fp user_table = (fp)d_in[5];
    fp item_table = (fp)d_in[6];
    fp cat_table  = (fp)d_in[7];
    fp Wih = (fp)d_in[8],  Whh = (fp)d_in[9];
    fp bih = (fp)d_in[10], bhh = (fp)d_in[11];
    fp Win = (fp)d_in[12], binp = (fp)d_in[13];
    fp Wout = (fp)d_in[14], bout = (fp)d_in[15];
    fp g1 = (fp)d_in[16], b1 = (fp)d_in[17];
    fp fc1W = (fp)d_in[18], fc1b = (fp)d_in[19];
    fp g2 = (fp)d_in[20], b2 = (fp)d_in[21];
    fp fc2W = (fp)d_in[22], fc2b = (fp)d_in[23];

    const int B = in_sizes[0];
    const int T = in_sizes[1] / B;

    float* ws       = (float*)d_ws;
    float* stats1   = ws;                       // 96
    float* stats2   = ws + 96;                  // 32
    float* all_enc  = ws + 128;                 // B*48 (16B aligned)
    float* hbuf     = all_enc + (size_t)B * 48; // B*16

    hipLaunchKernelGGL(k_zero, dim3(1), dim3(128), 0, stream, ws);

    hipLaunchKernelGGL(k_gru, dim3((B + 63) / 64), dim3(256), 0, stream,
                       user_id, hist_item, hist_cat, tgt_item, tgt_cat,
                       user_table, item_table, cat_table, Whh, bhh, Wih, bih,
                       Win, binp, Wout, bout, all_enc, stats1, B, T);

    hipLaunchKernelGGL(k_fc1, dim3(512), dim3(256), 0, stream,
                       all_enc, stats1, fc1W, fc1b, g1, b1, hbuf, stats2, B);

    hipLaunchKernelGGL(k_out, dim3((B + 255) / 256), dim3(256), 0, stream,
                       hbuf, stats2, fc2W, fc2b, g2, b2, (float*)d_out, B);
}

// Round 15
// 61.463 us; speedup vs baseline: 1.1620x; 1.0383x over previous
//
#include <hip/hip_runtime.h>

#define BN_EPS 1e-5f
#define LOG2E 1.44269504088896340736f

typedef const float* fp;
typedef float f32x4 __attribute__((ext_vector_type(4)));
typedef _Float16 f16x2 __attribute__((ext_vector_type(2)));
typedef _Float16 f16x4 __attribute__((ext_vector_type(4)));
typedef _Float16 f16x8 __attribute__((ext_vector_type(8)));
typedef unsigned u32x4 __attribute__((ext_vector_type(4)));

__device__ __forceinline__ float frcp(float x) { return __builtin_amdgcn_rcpf(x); }
__device__ __forceinline__ float fexp2(float x) { return __builtin_amdgcn_exp2f(x); }
// reference-formula transcendentals (used in k_out, unchanged)
__device__ __forceinline__ float sigm(float x) { return frcp(1.0f + __expf(-x)); }

__device__ __forceinline__ f32x4 ld4(const float* p) { return *(const f32x4*)p; }
__device__ __forceinline__ float dot4(f32x4 a, f32x4 b) {
    return a[0] * b[0] + a[1] * b[1] + a[2] * b[2] + a[3] * b[3];
}

#define MFMA32(A, B, C) __builtin_amdgcn_mfma_f32_16x16x32_f16((A), (B), (C), 0, 0, 0)

// async global->LDS, 16B per lane; dest = uniform base + lane*16 (HW rule).
#define GLDS16(gp, lp) __builtin_amdgcn_global_load_lds( \
    (const __attribute__((address_space(1))) void*)(gp), \
    (__attribute__((address_space(3))) void*)(lp), 16, 0, 0)

// pack f32x4 -> f16x4 via v_cvt_pkrtz (2 inst).
__device__ __forceinline__ f16x4 pk_f16(f32x4 v) {
    f16x2 lo = __builtin_bit_cast(f16x2, __builtin_amdgcn_cvt_pkrtz(v[0], v[1]));
    f16x2 hi = __builtin_bit_cast(f16x2, __builtin_amdgcn_cvt_pkrtz(v[2], v[3]));
    return __builtin_shufflevector(lo, hi, 0, 1, 2, 3);
}

// ---------------------------------------------------------------------------
// K0: zero stats1[96] + stats2[32].
// ---------------------------------------------------------------------------
__global__ void k_zero(float* __restrict__ stats) { stats[threadIdx.x] = 0.f; }

// ---------------------------------------------------------------------------
// K2: MFMA GRU, 16 samples/wave, 4-step unrolled 8-slot ring (R14 skeleton).
// NEW (trans cut 24->20/step + shorter chain):
//  - exp-scale constants folded into the WEIGHT fragments: r,z sets scaled by
//    -log2(e) so the MFMA output feeds v_exp (2^x) directly
//    (sigm(x)=1/(1+2^(-1.4427x))); n-gate set scaled by +2*log2(e)
//    (tanh(p)=1-2/(1+2^(2.8854p))). Removes 12 per-elem muls/step and one
//    mul from each serial trans sub-chain. Algebraically identical.
//  - shared rcp for r,z: iD=rcp((1+a)(1+b)); r=(1+b)iD; z=(1+a)iD
//    (8 rcp/step -> 4; overflow needs |preact|>88 — impossible at 0.1-scale
//    weights). tanh's rcp can't join (r feeds pre — circular).
// Same term set; absmax expected to stay 0.00390625. Requires T <= 52.
// ---------------------------------------------------------------------------
__device__ __forceinline__ void gru_step_h(
    f32x4 xr, f32x4 xz, f32x4 xn,
    const f16x8& Ahr, const f16x8& Ahz, const f16x8& Ahn, const f32x4& bhn4,
    f32x4& h, f32x4& hsum, f16x4& hh)
{
    f16x8 Bh2 = __builtin_shufflevector(hh, hh, 0, 1, 2, 3, 0, 1, 2, 3);
    f32x4 sR = MFMA32(Ahr, Bh2, xr);    // = -1.4427 * (r preact)
    f32x4 sZ = MFMA32(Ahz, Bh2, xz);    // = -1.4427 * (z preact)
    f32x4 hn = MFMA32(Ahn, Bh2, bhn4);  // =  2.8854 * (hn part)
    f32x4 r, z, nv;
#pragma unroll
    for (int q = 0; q < 4; ++q) {
        float a  = fexp2(sR[q]);
        float bb = fexp2(sZ[q]);
        float pa = 1.0f + a, pb = 1.0f + bb;
        float iD = frcp(pa * pb);
        r[q] = pb * iD;
        z[q] = pa * iD;
    }
    f32x4 pre = r * hn + xn;            // = 2.8854 * (n preact)
#pragma unroll
    for (int q = 0; q < 4; ++q)
        nv[q] = 1.0f - 2.0f * frcp(1.0f + fexp2(pre[q]));
    h = z * (h - nv) + nv;
    hsum += h;
    hh = pk_f16(h);
}

__global__ __launch_bounds__(256, 2) void k_gru(
    const int* __restrict__ user_id, const int* __restrict__ hist_item,
    const int* __restrict__ hist_cat, const int* __restrict__ tgt_item,
    const int* __restrict__ tgt_cat,
    fp user_table, fp item_table, fp cat_table,
    fp Whh, fp bhh, fp Wih, fp bih,
    fp mha_Win, fp mha_bin, fp mha_Wout, fp mha_bout,
    float* __restrict__ all_enc, float* __restrict__ stats1, int B, int T)
{
    __shared__ float    s_stage[4][8][256];   // 32KB [wave][slot][lane*4]
    __shared__ unsigned s_ids[4][16 * 68];    // 17.4KB packed (cd<<16)|id
    __shared__ float    lds_part[4][96];

    const int tid  = threadIdx.x;
    const int lane = tid & 63;
    const int wid  = tid >> 6;
    const int s    = lane & 15;
    const int hi   = lane >> 4;

    long b = (long)blockIdx.x * 64 + wid * 16 + s;
    const bool act = (b < B);
    if (!act) b = B - 1;

    // epilogue indices: materialize before the barrier (VMEM retires there)
    const int ti  = tgt_item[b];
    const int tc  = tgt_cat[b];
    const int uid = user_id[b];
    asm volatile("" :: "v"(ti), "v"(tc), "v"(uid));

    const int T1 = T - 1;

    // one-time packed id preload into LDS, padded with clamped ids to idx 63
    {
        const int* ip = hist_item + b * T;
        const int* cp = hist_cat  + b * T;
        unsigned* d = &s_ids[wid][s * 68];
        for (int k = hi; k < 64; k += 4) {
            int src = (k <= T1) ? k : T1;
            d[k] = (unsigned)ip[src] | ((unsigned)cp[src] << 16);
        }
    }

    // ---- weight fragments + constant gate biases (one-time) ----
    // exp-scales folded: r,z sets * -log2(e); n set * +2*log2(e).
    const float sRZ = -LOG2E, sN = 2.0f * LOG2E;
    f32x4 wirf = ld4(&Wih[(0  + s) * 16 + 4 * hi]) * sRZ;
    f32x4 wizf = ld4(&Wih[(16 + s) * 16 + 4 * hi]) * sRZ;
    f32x4 winf = ld4(&Wih[(32 + s) * 16 + 4 * hi]) * sN;
    f32x4 whrf = ld4(&Whh[(0  + s) * 16 + 4 * hi]) * sRZ;
    f32x4 whzf = ld4(&Whh[(16 + s) * 16 + 4 * hi]) * sRZ;
    f32x4 whnf = ld4(&Whh[(32 + s) * 16 + 4 * hi]) * sN;
    f16x4 wir_h = __builtin_convertvector(wirf, f16x4);
    f16x4 wiz_h = __builtin_convertvector(wizf, f16x4);
    f16x4 win_h = __builtin_convertvector(winf, f16x4);
    f16x4 whr_h = __builtin_convertvector(whrf, f16x4);
    f16x4 whz_h = __builtin_convertvector(whzf, f16x4);
    f16x4 whn_h = __builtin_convertvector(whnf, f16x4);
    f16x4 wir_l = __builtin_convertvector(wirf - __builtin_convertvector(wir_h, f32x4), f16x4);
    f16x4 wiz_l = __builtin_convertvector(wizf - __builtin_convertvector(wiz_h, f32x4), f16x4);
    f16x4 win_l = __builtin_convertvector(winf - __builtin_convertvector(win_h, f32x4), f16x4);
    f16x4 whr_l = __builtin_convertvector(whrf - __builtin_convertvector(whr_h, f32x4), f16x4);
    f16x4 whz_l = __builtin_convertvector(whzf - __builtin_convertvector(whz_h, f32x4), f16x4);
    f16x4 whn_l = __builtin_convertvector(whnf - __builtin_convertvector(whn_h, f32x4), f16x4);
    f16x8 Air = __builtin_shufflevector(wir_h, wir_l, 0, 1, 2, 3, 4, 5, 6, 7);
    f16x8 Aiz = __builtin_shufflevector(wiz_h, wiz_l, 0, 1, 2, 3, 4, 5, 6, 7);
    f16x8 Ain = __builtin_shufflevector(win_h, win_l, 0, 1, 2, 3, 4, 5, 6, 7);
    f16x8 Ahr = __builtin_shufflevector(whr_h, whr_l, 0, 1, 2, 3, 4, 5, 6, 7);
    f16x8 Ahz = __builtin_shufflevector(whz_h, whz_l, 0, 1, 2, 3, 4, 5, 6, 7);
    f16x8 Ahn = __builtin_shufflevector(whn_h, whn_l, 0, 1, 2, 3, 4, 5, 6, 7);
    const f32x4 br4  = (ld4(&bih[4 * hi])      + ld4(&bhh[4 * hi]))      * sRZ;
    const f32x4 bz4  = (ld4(&bih[16 + 4 * hi]) + ld4(&bhh[16 + 4 * hi])) * sRZ;
    const f32x4 bxn4 = ld4(&bih[32 + 4 * hi]) * sN;
    const f32x4 bhn4 = ld4(&bhh[32 + 4 * hi]) * sN;

    f32x4 h = {0.f, 0.f, 0.f, 0.f}, hsum = {0.f, 0.f, 0.f, 0.f};
    f16x4 hh = {};

    __syncthreads();   // ids ready; all prologue VMEM drained here

    const unsigned* idsrow = &s_ids[wid][s * 68];
    float* stg = &s_stage[wid][0][0];
    const int l4 = lane * 4;

    // per-lane gather parameters
    const char*   gb   = (hi < 3) ? (const char*)item_table + hi * 16
                                  : (const char*)cat_table;
    const unsigned gsh  = (hi < 3) ? 0u : 16u;
    const unsigned gmul = (hi < 3) ? 48u : 16u;
#define GADDR(pk) (gb + (size_t)(((pk) >> gsh) & 0xffffu) * gmul)

    // prologue: stage slots 0..7 (steps 0..7, clamped); prefetch ids[8..11]
    {
        u32x4 i03 = *(const u32x4*)&idsrow[0];
        u32x4 i47 = *(const u32x4*)&idsrow[4];
        GLDS16(GADDR(i03[0]), stg);
        GLDS16(GADDR(i03[1]), stg + 256);
        GLDS16(GADDR(i03[2]), stg + 512);
        GLDS16(GADDR(i03[3]), stg + 768);
        GLDS16(GADDR(i47[0]), stg + 1024);
        GLDS16(GADDR(i47[1]), stg + 1280);
        GLDS16(GADDR(i47[2]), stg + 1536);
        GLDS16(GADDR(i47[3]), stg + 1792);
    }
    u32x4 idn = *(const u32x4*)&idsrow[8];

    const int M    = T >> 2;   // full 4-step iterations
    const int tail = T & 3;

    for (int k = 0; k < M; ++k) {
        const int base = k << 2;
        asm volatile("s_waitcnt vmcnt(4)" ::: "memory");
        f32x4 e0 = ld4(stg + (((base + 0) & 7) << 8) + l4);
        f32x4 e1 = ld4(stg + (((base + 1) & 7) << 8) + l4);
        f32x4 e2 = ld4(stg + (((base + 2) & 7) << 8) + l4);
        f32x4 e3 = ld4(stg + (((base + 3) & 7) << 8) + l4);
        u32x4 idc = idn;
        idn = *(const u32x4*)&idsrow[base + 12];

        // ---- h-independent e-side MFMAs for all 4 steps (fill work) ----
        f16x4 eh0 = pk_f16(e0);
        f16x4 eh1 = pk_f16(e1);
        f16x4 eh2 = pk_f16(e2);
        f16x4 eh3 = pk_f16(e3);
        f16x8 Be0 = __builtin_shufflevector(eh0, eh0, 0, 1, 2, 3, 0, 1, 2, 3);
        f16x8 Be1 = __builtin_shufflevector(eh1, eh1, 0, 1, 2, 3, 0, 1, 2, 3);
        f16x8 Be2 = __builtin_shufflevector(eh2, eh2, 0, 1, 2, 3, 0, 1, 2, 3);
        f16x8 Be3 = __builtin_shufflevector(eh3, eh3, 0, 1, 2, 3, 0, 1, 2, 3);
        f32x4 xr0 = MFMA32(Air, Be0, br4),  xz0 = MFMA32(Aiz, Be0, bz4),  xn0 = MFMA32(Ain, Be0, bxn4);
        f32x4 xr1 = MFMA32(Air, Be1, br4),  xz1 = MFMA32(Aiz, Be1, bz4),  xn1 = MFMA32(Ain, Be1, bxn4);
        f32x4 xr2 = MFMA32(Air, Be2, br4),  xz2 = MFMA32(Aiz, Be2, bz4),  xn2 = MFMA32(Ain, Be2, bxn4);
        f32x4 xr3 = MFMA32(Air, Be3, br4),  xz3 = MFMA32(Aiz, Be3, bz4),  xn3 = MFMA32(Ain, Be3, bxn4);

        // ---- dependent recurrence: ONE MFMA per gate per step ----
        gru_step_h(xr0, xz0, xn0, Ahr, Ahz, Ahn, bhn4, h, hsum, hh);
        gru_step_h(xr1, xz1, xn1, Ahr, Ahz, Ahn, bhn4, h, hsum, hh);
        gru_step_h(xr2, xz2, xn2, Ahr, Ahz, Ahn, bhn4, h, hsum, hh);
        gru_step_h(xr3, xz3, xn3, Ahr, Ahz, Ahn, bhn4, h, hsum, hh);

        asm volatile("s_waitcnt lgkmcnt(0)" ::: "memory");
        GLDS16(GADDR(idc[0]), stg + (((base + 0) & 7) << 8));
        GLDS16(GADDR(idc[1]), stg + (((base + 1) & 7) << 8));
        GLDS16(GADDR(idc[2]), stg + (((base + 2) & 7) << 8));
        GLDS16(GADDR(idc[3]), stg + (((base + 3) & 7) << 8));
    }
    if (tail) {
        asm volatile("s_waitcnt vmcnt(0)" ::: "memory");
        for (int t = M << 2; t < T; ++t) {
            f32x4 e = ld4(stg + ((t & 7) << 8) + l4);
            f16x4 eh = pk_f16(e);
            f16x8 Be = __builtin_shufflevector(eh, eh, 0, 1, 2, 3, 0, 1, 2, 3);
            f32x4 xr = MFMA32(Air, Be, br4);
            f32x4 xz = MFMA32(Aiz, Be, bz4);
            f32x4 xn = MFMA32(Ain, Be, bxn4);
            gru_step_h(xr, xz, xn, Ahr, Ahz, Ahn, bhn4, h, hsum, hh);
        }
    }

    // ---- epilogue: degenerate MHA -> A[b], all_enc row, BN1 stats ----
    const float* itr = item_table + (size_t)ti * 12;
    f32x4 tv0 = ld4(itr), tv1 = ld4(itr + 4), tv2 = ld4(itr + 8);
    f32x4 tv3 = ld4(cat_table + tc * 4);

    f32x4 vq;
#pragma unroll
    for (int q = 0; q < 4; ++q) {
        int row = 32 + 4 * hi + q;
        const float* wv = mha_Win + row * 16;
        vq[q] = mha_bin[row] + dot4(ld4(wv), tv0) + dot4(ld4(wv + 4), tv1)
              + dot4(ld4(wv + 8), tv2) + dot4(ld4(wv + 12), tv3);
    }
    f32x4 vg0, vg1, vg2, vg3;
#pragma unroll
    for (int q = 0; q < 4; ++q) {
        vg0[q] = __shfl_xor(vq[q], (hi ^ 0) << 4);
        vg1[q] = __shfl_xor(vq[q], (hi ^ 1) << 4);
        vg2[q] = __shfl_xor(vq[q], (hi ^ 2) << 4);
        vg3[q] = __shfl_xor(vq[q], (hi ^ 3) << 4);
    }
    f32x4 aj;
#pragma unroll
    for (int q = 0; q < 4; ++q) {
        int row = 4 * hi + q;
        const float* wo = mha_Wout + row * 16;
        aj[q] = mha_bout[row] + dot4(ld4(wo), vg0) + dot4(ld4(wo + 4), vg1)
              + dot4(ld4(wo + 8), vg2) + dot4(ld4(wo + 12), vg3);
    }
    f32x4 avg = aj * hsum;

    f32x4 u4  = ld4(user_table + (size_t)uid * 16 + 4 * hi);
    f32x4 t4v = (hi == 0) ? tv0 : (hi == 1) ? tv1 : (hi == 2) ? tv2 : tv3;

    if (act) {
        float* er = all_enc + b * 48 + 4 * hi;
        *(f32x4*)er        = avg;
        *(f32x4*)(er + 16) = t4v;
        *(f32x4*)(er + 32) = u4;
    }

    const f32x4 zero4 = {0.f, 0.f, 0.f, 0.f};
    f32x4 sa = act ? avg : zero4, st = act ? t4v : zero4, su = act ? u4 : zero4;
    f32x4 qa = sa * sa, qt = st * st, qu = su * su;
#pragma unroll
    for (int m = 1; m <= 8; m <<= 1) {
#pragma unroll
        for (int q = 0; q < 4; ++q) {
            sa[q] += __shfl_xor(sa[q], m);
            st[q] += __shfl_xor(st[q], m);
            su[q] += __shfl_xor(su[q], m);
            qa[q] += __shfl_xor(qa[q], m);
            qt[q] += __shfl_xor(qt[q], m);
            qu[q] += __shfl_xor(qu[q], m);
        }
    }
    if (s == 0) {
        int c = 4 * hi;
#pragma unroll
        for (int q = 0; q < 4; ++q) {
            lds_part[wid][c + q]      = sa[q];
            lds_part[wid][16 + c + q] = st[q];
            lds_part[wid][32 + c + q] = su[q];
            lds_part[wid][48 + c + q] = qa[q];
            lds_part[wid][64 + c + q] = qt[q];
            lds_part[wid][80 + c + q] = qu[q];
        }
    }
    __syncthreads();
    if (tid < 96) {
        float v = lds_part[0][tid] + lds_part[1][tid] + lds_part[2][tid] + lds_part[3][tid];
        atomicAdd(&stats1[tid], v);
    }
}

// ---------------------------------------------------------------------------
// K3: fc1 with BN1-fold computed inline per block (512 blocks).
// ---------------------------------------------------------------------------
__global__ __launch_bounds__(256) void k_fc1(
    const float* __restrict__ all_enc, const float* __restrict__ stats,
    fp fc1_W, fp fc1_b, fp g1, fp b1,
    float* __restrict__ hbuf, float* __restrict__ stats2, int B)
{
    const int tid = threadIdx.x, lane = tid & 63, wid = tid >> 6;
    const int j = lane & 15, sl = lane >> 4;
    __shared__ float kk[48], mm[48];
    __shared__ float part[4][32];

    if (tid < 48) {
        float mu  = stats[tid] / (float)B;
        float var = stats[48 + tid] / (float)B - mu * mu;
        float k   = rsqrtf(var + BN_EPS);
        float gk  = g1[tid] * k;
        kk[tid] = gk;
        mm[tid] = b1[tid] - mu * gk;
    }
    __syncthreads();

    float w[48];
    float bj = fc1_b[j];
#pragma unroll
    for (int q = 0; q < 12; ++q) {
        float4 v = *(const float4*)&fc1_W[j * 48 + q * 4];
        w[q * 4 + 0] = v.x * kk[q * 4 + 0];
        w[q * 4 + 1] = v.y * kk[q * 4 + 1];
        w[q * 4 + 2] = v.z * kk[q * 4 + 2];
        w[q * 4 + 3] = v.w * kk[q * 4 + 3];
        bj += v.x * mm[q * 4 + 0] + v.y * mm[q * 4 + 1]
            + v.z * mm[q * 4 + 2] + v.w * mm[q * 4 + 3];
    }

    float sh = 0.f, sq = 0.f;
    for (long b = (long)blockIdx.x * 16 + wid * 4 + sl; b < B; b += (long)gridDim.x * 16) {
        const float* x = all_enc + b * 48;
        float acc = bj;
#pragma unroll
        for (int q = 0; q < 12; ++q) {
            float4 v = *(const float4*)&x[q * 4];
            acc += w[q * 4] * v.x + w[q * 4 + 1] * v.y + w[q * 4 + 2] * v.z + w[q * 4 + 3] * v.w;
        }
        float h = fmaxf(acc, 0.f);
        hbuf[b * 16 + j] = h;
        sh += h; sq += h * h;
    }
    sh += __shfl_xor(sh, 16); sh += __shfl_xor(sh, 32);
    sq += __shfl_xor(sq, 16); sq += __shfl_xor(sq, 32);
    if (sl == 0) { part[wid][j] = sh; part[wid][16 + j] = sq; }
    __syncthreads();
    if (tid < 32) {
        float v = part[0][tid] + part[1][tid] + part[2][tid] + part[3][tid];
        atomicAdd(&stats2[tid], v);
    }
}

// ---------------------------------------------------------------------------
// K4: logits + softmax, BN2-fold computed inline per block.
// ---------------------------------------------------------------------------
__global__ __launch_bounds__(256) void k_out(
    const float* __restrict__ hbuf, const float* __restrict__ stats2,
    fp fc2_W, fp fc2_b, fp g2, fp b2, float* __restrict__ out, int B)
{
    __shared__ float w[34];
    const int tid = threadIdx.x;
    if (tid < 32) {
        int c = tid & 15;
        float mu  = stats2[c] / (float)B;
        float var = stats2[16 + c] / (float)B - mu * mu;
        float gk  = g2[c] * rsqrtf(var + BN_EPS);
        w[tid] = fc2_W[tid] * gk;
    }
    if (tid < 2) {
        float acc = fc2_b[tid];
        for (int c = 0; c < 16; ++c) {
            float mu  = stats2[c] / (float)B;
            float var = stats2[16 + c] / (float)B - mu * mu;
            float gk  = g2[c] * rsqrtf(var + BN_EPS);
            acc += fc2_W[tid * 16 + c] * (b2[c] - mu * gk);
        }
        w[32 + tid] = acc;
    }
    __syncthreads();
    for (long b = (long)blockIdx.x * blockDim.x + threadIdx.x; b < B;
         b += (long)gridDim.x * blockDim.x) {
        const float* h = hbuf + b * 16;
        float l0 = w[32], l1 = w[33];
#pragma unroll
        for (int q = 0; q < 4; ++q) {
            float4 v = *(const float4*)&h[q * 4];
            l0 += w[q * 4] * v.x + w[q * 4 + 1] * v.y + w[q * 4 + 2] * v.z + w[q * 4 + 3] * v.w;
            l1 += w[16 + q * 4] * v.x + w[17 + q * 4] * v.y + w[18 + q * 4] * v.z + w[19 + q * 4] * v.w;
        }
        float m  = fmaxf(l0, l1);
        float e0 = __expf(l0 - m), e1 = __expf(l1 - m);
        float inv = frcp(e0 + e1);
        float2 p; p.x = e0 * inv; p.y = e1 * inv;
        *(float2*)&out[b * 2] = p;
    }
}

// ---------------------------------------------------------------------------
extern "C" void kernel_launch(void* const* d_in, const int* in_sizes, int n_in,
                              void* d_out, int out_size, void* d_ws, size_t ws_size,
                              hipStream_t stream)
{
    const int* user_id   = (const int*)d_in[0];
    const int* hist_item = (const int*)d_in[1];
    const int* hist_cat  = (const int*)d_in[2];
    const int* tgt_item  = (const int*)d_in[3];
    const int* tgt_cat   = (const int*)d_in[4];
    fp user_table = (fp)d_in[5];
    fp item_table = (fp)d_in[6];
    fp cat_table  = (fp)d_in[7];
    fp Wih = (fp)d_in[8],  Whh = (fp)d_in[9];
    fp bih = (fp)d_in[10], bhh = (fp)d_in[11];
    fp Win = (fp)d_in[12], binp = (fp)d_in[13];
    fp Wout = (fp)d_in[14], bout = (fp)d_in[15];
    fp g1 = (fp)d_in[16], b1 = (fp)d_in[17];
    fp fc1W = (fp)d_in[18], fc1b = (fp)d_in[19];
    fp g2 = (fp)d_in[20], b2 = (fp)d_in[21];
    fp fc2W = (fp)d_in[22], fc2b = (fp)d_in[23];

    const int B = in_sizes[0];
    const int T = in_sizes[1] / B;

    float* ws       = (float*)d_ws;
    float* stats1   = ws;                       // 96
    float* stats2   = ws + 96;                  // 32
    float* all_enc  = ws + 128;                 // B*48 (16B aligned)
    float* hbuf     = all_enc + (size_t)B * 48; // B*16

    hipLaunchKernelGGL(k_zero, dim3(1), dim3(128), 0, stream, ws);

    hipLaunchKernelGGL(k_gru, dim3((B + 63) / 64), dim3(256), 0, stream,
                       user_id, hist_item, hist_cat, tgt_item, tgt_cat,
                       user_table, item_table, cat_table, Whh, bhh, Wih, bih,
                       Win, binp, Wout, bout, all_enc, stats1, B, T);

    hipLaunchKernelGGL(k_fc1, dim3(512), dim3(256), 0, stream,
                       all_enc, stats1, fc1W, fc1b, g1, b1, hbuf, stats2, B);

    hipLaunchKernelGGL(k_out, dim3((B + 255) / 256), dim3(256), 0, stream,
                       hbuf, stats2, fc2W, fc2b, g2, b2, (float*)d_out, B);
}